// Round 5
// baseline (537.646 us; speedup 1.0000x reference)
//
#include <hip/hip_runtime.h>

#define B 4
#define C 48
#define C3 144
#define H 256
#define W 256
#define HW 65536
#define EPSN 1e-12f

// ---- a1 tiling (Path A fallback) ----
#define TSX 16
#define TSY 12
#define HSX 18
#define HSY 14
#define NTX 16
#define NTY 22
#define NPIX2 192
#define NHALO 252

#define NCHUNK 128       // Path-A gram chunks per batch
#define CHUNK 512        // Path-A pixels per gram chunk
#define LP 68            // Path-A a2 LDS stride

// ---- S path (round-11) ----
// Round-11 theory: every kernel sits at ~2-3.3 TB/s effective; micro-structure
// (occupancy, pipe mix) keeps under-delivering. The dependable lever is BYTES.
// dwq/dwk exist only to carry s_dw's output to a2_gram (100 MB write + 100 MB
// read). Fuse: s_dwgram = per-image-row block, dw for all 144 ch via direct
// bounded global reads (vertical re-reads are L3-absorbed: qkv 151 MB < 256 MB
// L3, proven by s_dw's FETCH 82<151 MB), q/k dw outputs staged in a 50.7 KB
// LDS tile (LP2=132 -> gram reads bank-clean), 48x48 gram + norms accumulated
// in registers, only v + tiny partials written. dwq/dwk never materialize.
#define NCH2 256         // fused-path chunks per batch = image rows
#define LP2 132          // padded LDS stride (bank-verified: k-reads 2-phase min)

// ================= PATH S workspace layout (floats), ~161 MB =================
#define S_QKV_OFF  ((size_t)0)
#define S_SP_OFF   (S_QKV_OFF + (size_t)B * C3 * HW)
#define S_NQP_OFF  (S_SP_OFF + (size_t)B * NCH2 * C * C)
#define S_NKP_OFF  (S_NQP_OFF + (size_t)B * NCH2 * C)
#define S_S_OFF    (S_NKP_OFF + (size_t)B * NCH2 * C)
#define S_NQ_OFF   (S_S_OFF + (size_t)B * C * C)
#define S_NK_OFF   (S_NQ_OFF + (size_t)B * C)
#define S_M_OFF    (S_NK_OFF + (size_t)B * C)
#define S_WT_OFF   (S_M_OFF + (size_t)B * C * C)
#define S_FLOATS   (S_WT_OFF + (size_t)C3 * C)

// ================= PATH A workspace layout (floats), ~106 MB =================
#define A_DWQ_OFF  ((size_t)0)
#define A_DWK_OFF  (A_DWQ_OFF + (size_t)B * C * HW)
#define A_SP_OFF   (A_DWK_OFF + (size_t)B * C * HW)
#define A_NQP_OFF  (A_SP_OFF + (size_t)B * NCHUNK * C * C)
#define A_NKP_OFF  (A_NQP_OFF + (size_t)B * NCHUNK * C)
#define A_S_OFF    (A_NKP_OFF + (size_t)B * NCHUNK * C)
#define A_NQ_OFF   (A_S_OFF + (size_t)B * C * C)
#define A_NK_OFF   (A_NQ_OFF + (size_t)B * C)
#define A_M_OFF    (A_NK_OFF + (size_t)B * C)
#define A_FLOATS   (A_M_OFF + (size_t)B * C * C)

// ================= PATH B (fallback) workspace layout, ~75 KB ================
#define B_S_OFF  0
#define B_NQ_OFF (B * C * C)
#define B_NK_OFF (B_NQ_OFF + B * C)
#define B_M_OFF  (B_NK_OFF + B * C)
#define B_ZERO_N (B * C * C + 2 * B * C)

// ============================ PATH S kernels =================================

// S0: transpose qkv 1x1 weights [144][48] -> wT [48][144].
__global__ __launch_bounds__(256) void s_wt(
    const float* __restrict__ w1, float* __restrict__ wT) {
  const int i = blockIdx.x * 256 + threadIdx.x;
  if (i < C3 * C) {
    const int oc = i / C, d = i - oc * C;
    wT[d * C3 + oc] = w1[i];
  }
}

// S1: 1x1 conv as GEMM. 128-px tile (24 KB LDS -> 6 blocks/CU), thread owns
// 2 px, wave owns 12 oc x 3 groups; weights via wave-uniform s_load.
__global__ __launch_bounds__(256) void s_conv1x1(
    const float* __restrict__ x, const float* __restrict__ wT,
    float* __restrict__ qkv) {
  __shared__ float xs[C * 128];      // 24 KB
  const int t = threadIdx.x;
  const int bb = blockIdx.x >> 9;                // 512 pixel-tiles per batch
  const int p0 = (blockIdx.x & 511) << 7;        // 128 px per tile
  const float* xb = x + (size_t)bb * C * HW + p0;
#pragma unroll
  for (int j = 0; j < 6; ++j) {                  // 1536 float4 = 48x128
    const int f = t + j * 256;
    const int d = f >> 5, p4 = (f & 31) * 4;
    *(float4*)&xs[d * 128 + p4] = *(const float4*)&xb[(size_t)d * HW + p4];
  }
  __syncthreads();
  const int pl = (t & 63) * 2;                   // this thread's 2 pixels
  const int ocw = __builtin_amdgcn_readfirstlane((t >> 6) * 12);
#pragma unroll 1
  for (int g = 0; g < 3; ++g) {
    const int oc0 = g * 48 + ocw;                // provably wave-uniform
    const float* wp = wT + oc0;                  // uniform -> s_load base
    float acc[12][2];
#pragma unroll
    for (int o = 0; o < 12; ++o)
#pragma unroll
      for (int p = 0; p < 2; ++p) acc[o][p] = 0.f;
#pragma unroll 4
    for (int d = 0; d < C; ++d) {
      const float2 xv = *(const float2*)&xs[d * 128 + pl];
      const float xa[2] = {xv.x, xv.y};
#pragma unroll
      for (int jj = 0; jj < 3; ++jj) {
        const float4 wv = *(const float4*)&wp[d * C3 + jj * 4];
        const float wa[4] = {wv.x, wv.y, wv.z, wv.w};
#pragma unroll
        for (int o = 0; o < 4; ++o)
#pragma unroll
          for (int p = 0; p < 2; ++p)
            acc[jj * 4 + o][p] = fmaf(wa[o], xa[p], acc[jj * 4 + o][p]);
      }
    }
    float* ob = qkv + ((size_t)bb * C3 + oc0) * HW + p0 + pl;
#pragma unroll
    for (int o = 0; o < 12; ++o) {
      float2 v;
      v.x = acc[o][0]; v.y = acc[o][1];
      *(float2*)&ob[(size_t)o * HW] = v;
    }
  }
}

// S2': fused depthwise 3x3 + Gram partials + norms. Block = (batch, image
// row y); two 128-px sub-tiles. dw inputs read directly from global with
// bounds (L1/L2/L3-cached; vertical re-reads are L3 hits). q/k dw outputs
// -> LDS qk[96][LP2]; v dw outputs -> global (out buffer). Gram 48x48 and
// sum-of-squares accumulated in registers across sub-tiles; one partial
// row written per block. dwq/dwk never materialize.
__global__ __launch_bounds__(256) void s_dwgram(
    const float* __restrict__ qkv, const float* __restrict__ w9,
    float* __restrict__ vout, float* __restrict__ Sp,
    float* __restrict__ nqp, float* __restrict__ nkp) {
  __shared__ float qk[96 * LP2];     // 50.7 KB
  const int t = threadIdx.x;
  const int bb = blockIdx.x >> 8;
  const int y  = blockIdx.x & 255;
  const float* qb = qkv + (size_t)bb * C3 * HW;
  const int lx = t & 127;            // local col in sub-tile
  const int chH = t >> 7;            // wave-uniform (waves 0,1 -> 0; 2,3 -> 1)
  const int c0 = (t >> 4) * 3;       // gram mapping (as a2)
  const int d0 = (t & 15) * 3;
  float acc[3][3] = {{0.f}};
  float nacc = 0.f;
#pragma unroll 1
  for (int sub = 0; sub < 2; ++sub) {
    const int x = sub * 128 + lx;
    const bool okm = (x > 0);
    const bool okp = (x < W - 1);
    __syncthreads();                 // LDS free (prev sub's gram reads done)
    // ---- dw for 144 channels, 2 per pass (one per wave-pair) ----
#pragma unroll 2
    for (int cp = 0; cp < 72; ++cp) {
      const int ch = cp * 2 + chH;   // wave-uniform
      const float* wp = w9 + ch * 9; // -> s_load
      float wv[9];
#pragma unroll
      for (int k2 = 0; k2 < 9; ++k2) wv[k2] = wp[k2];
      float s = 0.f;
#pragma unroll
      for (int dy = 0; dy < 3; ++dy) {
        const int ry = y + dy - 1;
        if (ry >= 0 && ry < H) {     // uniform branch
          const float* r = qb + (size_t)ch * HW + ry * W;
          const float vm = okm ? r[x - 1] : 0.f;
          const float vc = r[x];
          const float vp = okp ? r[x + 1] : 0.f;
          s = fmaf(wv[dy * 3 + 0], vm, s);
          s = fmaf(wv[dy * 3 + 1], vc, s);
          s = fmaf(wv[dy * 3 + 2], vp, s);
        }
      }
      if (ch < 96) qk[ch * LP2 + lx] = s;   // q rows 0..47, k rows 48..95
      else vout[((size_t)bb * C + (ch - 96)) * HW + y * W + x] = s;
    }
    __syncthreads();
    // ---- norms (threads 0..47 q, 64..111 k) ----
    if (t < C) {
#pragma unroll
      for (int pq = 0; pq < 128; pq += 4) {
        const float4 v = *(const float4*)&qk[t * LP2 + pq];
        nacc = fmaf(v.x, v.x, nacc);
        nacc = fmaf(v.y, v.y, nacc);
        nacc = fmaf(v.z, v.z, nacc);
        nacc = fmaf(v.w, v.w, nacc);
      }
    } else if (t >= 64 && t < 64 + C) {
      const int cq = 48 + (t - 64);
#pragma unroll
      for (int pq = 0; pq < 128; pq += 4) {
        const float4 v = *(const float4*)&qk[cq * LP2 + pq];
        nacc = fmaf(v.x, v.x, nacc);
        nacc = fmaf(v.y, v.y, nacc);
        nacc = fmaf(v.z, v.z, nacc);
        nacc = fmaf(v.w, v.w, nacc);
      }
    }
    // ---- gram 48x48, 3x3 micro-tile per thread ----
#pragma unroll 4
    for (int pq = 0; pq < 128; pq += 4) {
      const float4 q0 = *(const float4*)&qk[(c0 + 0) * LP2 + pq];
      const float4 q1 = *(const float4*)&qk[(c0 + 1) * LP2 + pq];
      const float4 q2 = *(const float4*)&qk[(c0 + 2) * LP2 + pq];
      const float4 k0 = *(const float4*)&qk[(48 + d0 + 0) * LP2 + pq];
      const float4 k1 = *(const float4*)&qk[(48 + d0 + 1) * LP2 + pq];
      const float4 k2 = *(const float4*)&qk[(48 + d0 + 2) * LP2 + pq];
      const float qa[3][4] = {{q0.x, q0.y, q0.z, q0.w},
                              {q1.x, q1.y, q1.z, q1.w},
                              {q2.x, q2.y, q2.z, q2.w}};
      const float ka[3][4] = {{k0.x, k0.y, k0.z, k0.w},
                              {k1.x, k1.y, k1.z, k1.w},
                              {k2.x, k2.y, k2.z, k2.w}};
#pragma unroll
      for (int p = 0; p < 4; ++p)
#pragma unroll
        for (int i = 0; i < 3; ++i)
#pragma unroll
          for (int j = 0; j < 3; ++j)
            acc[i][j] = fmaf(qa[i][p], ka[j][p], acc[i][j]);
    }
  }
  float* Sb = Sp + ((size_t)bb * NCH2 + y) * C * C;
#pragma unroll
  for (int i = 0; i < 3; ++i)
#pragma unroll
    for (int j = 0; j < 3; ++j)
      Sb[(c0 + i) * C + (d0 + j)] = acc[i][j];
  if (t < C)                        nqp[((size_t)bb * NCH2 + y) * C + t] = nacc;
  else if (t >= 64 && t < 64 + C)   nkp[((size_t)bb * NCH2 + y) * C + (t - 64)] = nacc;
}

// ============================ PATH A kernels =================================

// A1: 1x1 conv + depthwise 3x3 fused (fallback path only).
__global__ __launch_bounds__(256) void a1_conv_dw(
    const float* __restrict__ x, const float* __restrict__ w1,
    const float* __restrict__ w9, float* __restrict__ dwq,
    float* __restrict__ dwk, float* __restrict__ vout) {
  __shared__ float xs[C * 256];
  __shared__ float qs[8 * 256];
  __shared__ float wg[C * 8];
  __shared__ float wg9[8 * 9];
  const int t = threadIdx.x;
  const int bb = blockIdx.x / (NTX * NTY);
  const int tile = blockIdx.x % (NTX * NTY);
  const int ty = tile / NTX, tx = tile % NTX;
  const int hyy = t / HSX, hxx = t % HSX;
  const int hy = ty * TSY - 1 + hyy;
  const int hx = tx * TSX - 1 + hxx;
  const bool hin = (t < NHALO) && (hy >= 0) && (hy < H) && (hx >= 0) && (hx < W);
  const float* xb = x + (size_t)bb * C * HW + (hin ? (hy * W + hx) : 0);
#pragma unroll
  for (int ic = 0; ic < C; ++ic)
    xs[ic * 256 + t] = hin ? xb[(size_t)ic * HW] : 0.f;
  const int py = t / TSX, px = t % TSX;
  const int gy = ty * TSY + py, gx = tx * TSX + px;
  const bool pin = (t < NPIX2) && (gy < H);
  const int hpos = py * HSX + px;
  for (int grp = 0; grp < 18; ++grp) {
    const int ch0 = grp * 8;
    {
      const int j = t + ((t < 128) ? 256 : 0);
      if (t < 128) {
        const int ic = t >> 3, g = t & 7;
        wg[t] = w1[(ch0 + g) * C + ic];
        const int ic2 = j >> 3, g2 = j & 7;
        wg[j] = w1[(ch0 + g2) * C + ic2];
      } else if (t < 256) {
        const int r = t - 128;
        const int ic = (r + 128) >> 3, g = (r + 128) & 7;
        wg[r + 128] = w1[(ch0 + g) * C + ic];
      }
      if (t < 72) wg9[t] = w9[ch0 * 9 + t];
    }
    __syncthreads();
    float a[8];
#pragma unroll
    for (int g = 0; g < 8; ++g) a[g] = 0.f;
#pragma unroll 4
    for (int ic = 0; ic < C; ++ic) {
      const float xsv = xs[ic * 256 + t];
      const float4 w0 = *(const float4*)&wg[ic * 8];
      const float4 w4 = *(const float4*)&wg[ic * 8 + 4];
      a[0] = fmaf(w0.x, xsv, a[0]);
      a[1] = fmaf(w0.y, xsv, a[1]);
      a[2] = fmaf(w0.z, xsv, a[2]);
      a[3] = fmaf(w0.w, xsv, a[3]);
      a[4] = fmaf(w4.x, xsv, a[4]);
      a[5] = fmaf(w4.y, xsv, a[5]);
      a[6] = fmaf(w4.z, xsv, a[6]);
      a[7] = fmaf(w4.w, xsv, a[7]);
    }
#pragma unroll
    for (int g = 0; g < 8; ++g) qs[g * 256 + t] = a[g];
    __syncthreads();
    if (t < NPIX2) {
#pragma unroll
      for (int g = 0; g < 8; ++g) {
        const int ch = ch0 + g;
        const float* w9p = wg9 + g * 9;
        const float* q = qs + g * 256 + hpos;
        float d = w9p[0] * q[0] + w9p[1] * q[1] + w9p[2] * q[2];
        d = fmaf(w9p[3], q[HSX], d);
        d = fmaf(w9p[4], q[HSX + 1], d);
        d = fmaf(w9p[5], q[HSX + 2], d);
        d = fmaf(w9p[6], q[2 * HSX], d);
        d = fmaf(w9p[7], q[2 * HSX + 1], d);
        d = fmaf(w9p[8], q[2 * HSX + 2], d);
        if (pin) {
          float* dst;
          int cc;
          if (ch < C)          { dst = dwq; cc = ch; }
          else if (ch < 2 * C) { dst = dwk; cc = ch - C; }
          else                 { dst = vout; cc = ch - 2 * C; }
          dst[((size_t)bb * C + cc) * HW + gy * W + gx] = d;
        }
      }
    }
    __syncthreads();
  }
}

// A2: per-chunk Gram partials + norm partials (Path A only).
__global__ __launch_bounds__(256) void a2_gram(
    const float* __restrict__ dwq, const float* __restrict__ dwk,
    float* __restrict__ Sp, float* __restrict__ nqp, float* __restrict__ nkp) {
  __shared__ float qs[C * LP];
  __shared__ float ks[C * LP];
  const int tid = threadIdx.x;
  const int bb = blockIdx.x / NCHUNK;
  const int chunk = blockIdx.x % NCHUNK;
  const int base = chunk * CHUNK;
  const float* qb = dwq + (size_t)bb * C * HW + base;
  const float* kb = dwk + (size_t)bb * C * HW + base;
  const int c0 = (tid >> 4) * 3;
  const int d0 = (tid & 15) * 3;
  float acc[3][3] = {{0.f}};
  float nacc = 0.f;
  float4 rq[3], rk[3];
#pragma unroll
  for (int j = 0; j < 3; ++j) {
    const int f = tid + j * 256;
    const int cc = f >> 4, p4 = (f & 15) * 4;
    rq[j] = *(const float4*)&qb[(size_t)cc * HW + p4];
    rk[j] = *(const float4*)&kb[(size_t)cc * HW + p4];
  }
  for (int sub = 0; sub < CHUNK / 64; ++sub) {
    __syncthreads();
#pragma unroll
    for (int j = 0; j < 3; ++j) {
      const int f = tid + j * 256;
      const int cc = f >> 4, p4 = (f & 15) * 4;
      *(float4*)&qs[cc * LP + p4] = rq[j];
      *(float4*)&ks[cc * LP + p4] = rk[j];
    }
    if (sub < CHUNK / 64 - 1) {
#pragma unroll
      for (int j = 0; j < 3; ++j) {
        const int f = tid + j * 256;
        const int cc = f >> 4, p4 = (f & 15) * 4;
        rq[j] = *(const float4*)&qb[(size_t)cc * HW + (sub + 1) * 64 + p4];
        rk[j] = *(const float4*)&kb[(size_t)cc * HW + (sub + 1) * 64 + p4];
      }
    }
    __syncthreads();
    if (tid < C) {
#pragma unroll
      for (int pq = 0; pq < 64; pq += 4) {
        const float4 v = *(const float4*)&qs[tid * LP + pq];
        nacc = fmaf(v.x, v.x, nacc);
        nacc = fmaf(v.y, v.y, nacc);
        nacc = fmaf(v.z, v.z, nacc);
        nacc = fmaf(v.w, v.w, nacc);
      }
    } else if (tid >= 64 && tid < 64 + C) {
      const int cq = tid - 64;
#pragma unroll
      for (int pq = 0; pq < 64; pq += 4) {
        const float4 v = *(const float4*)&ks[cq * LP + pq];
        nacc = fmaf(v.x, v.x, nacc);
        nacc = fmaf(v.y, v.y, nacc);
        nacc = fmaf(v.z, v.z, nacc);
        nacc = fmaf(v.w, v.w, nacc);
      }
    }
#pragma unroll 4
    for (int pq = 0; pq < 64; pq += 4) {
      const float4 q0 = *(const float4*)&qs[(c0 + 0) * LP + pq];
      const float4 q1 = *(const float4*)&qs[(c0 + 1) * LP + pq];
      const float4 q2 = *(const float4*)&qs[(c0 + 2) * LP + pq];
      const float4 k0 = *(const float4*)&ks[(d0 + 0) * LP + pq];
      const float4 k1 = *(const float4*)&ks[(d0 + 1) * LP + pq];
      const float4 k2 = *(const float4*)&ks[(d0 + 2) * LP + pq];
      const float qa[3][4] = {{q0.x, q0.y, q0.z, q0.w},
                              {q1.x, q1.y, q1.z, q1.w},
                              {q2.x, q2.y, q2.z, q2.w}};
      const float ka[3][4] = {{k0.x, k0.y, k0.z, k0.w},
                              {k1.x, k1.y, k1.z, k1.w},
                              {k2.x, k2.y, k2.z, k2.w}};
#pragma unroll
      for (int p = 0; p < 4; ++p)
#pragma unroll
        for (int i = 0; i < 3; ++i)
#pragma unroll
          for (int j = 0; j < 3; ++j)
            acc[i][j] = fmaf(qa[i][p], ka[j][p], acc[i][j]);
    }
  }
  float* Sb = Sp + ((size_t)bb * NCHUNK + chunk) * C * C;
#pragma unroll
  for (int i = 0; i < 3; ++i)
#pragma unroll
    for (int j = 0; j < 3; ++j)
      Sb[(c0 + i) * C + (d0 + j)] = acc[i][j];
  if (tid < C)                        nqp[((size_t)bb * NCHUNK + chunk) * C + tid] = nacc;
  else if (tid >= 64 && tid < 64 + C) nkp[((size_t)bb * NCHUNK + chunk) * C + (tid - 64)] = nacc;
}

// A3a: flat parallel reduction of the chunk partials (nchunk runtime).
#define RED_N (B * C * C + 2 * B * C)   // 9600
__global__ __launch_bounds__(256) void a3a_reduce(
    const float* __restrict__ Sp, const float* __restrict__ nqp,
    const float* __restrict__ nkp, float* __restrict__ S,
    float* __restrict__ nq, float* __restrict__ nk, int nchunk) {
  const int gid = blockIdx.x * 256 + threadIdx.x;
  if (gid < B * C * C) {
    const int bb = gid / (C * C), j = gid - bb * (C * C);
    const float* src = Sp + (size_t)bb * nchunk * C * C + j;
    float s = 0.f;
#pragma unroll 8
    for (int i = 0; i < nchunk; ++i) s += src[(size_t)i * C * C];
    S[gid] = s;
  } else if (gid < B * C * C + B * C) {
    const int r = gid - B * C * C;
    const int bb = r / C, j = r - bb * C;
    const float* src = nqp + (size_t)bb * nchunk * C + j;
    float s = 0.f;
#pragma unroll 8
    for (int i = 0; i < nchunk; ++i) s += src[(size_t)i * C];
    nq[r] = s;
  } else if (gid < RED_N) {
    const int r = gid - B * C * C - B * C;
    const int bb = r / C, j = r - bb * C;
    const float* src = nkp + (size_t)bb * nchunk * C + j;
    float s = 0.f;
#pragma unroll 8
    for (int i = 0; i < nchunk; ++i) s += src[(size_t)i * C];
    nk[r] = s;
  }
}

// A3b: normalize S, softmax rows, fold proj; writes transposed MT[d][e].
__global__ __launch_bounds__(64) void a3b_attn(
    const float* __restrict__ S, const float* __restrict__ nq,
    const float* __restrict__ nk, const float* __restrict__ proj_w,
    const float* __restrict__ temperature, float* __restrict__ MT) {
  __shared__ float A[C * C];
  __shared__ float knl[C];
  const int bb = blockIdx.x;
  const int t = threadIdx.x;
  const float T = temperature[0];
  if (t < C) knl[t] = fmaxf(sqrtf(nk[bb * C + t]), EPSN);
  __syncthreads();
  if (t < C) {
    const float qn = fmaxf(sqrtf(nq[bb * C + t]), EPSN);
    float row[C];
    float m = -1e30f;
    for (int d = 0; d < C; ++d) {
      const float v = S[(size_t)bb * C * C + t * C + d] / (qn * knl[d]) * T;
      row[d] = v;
      m = fmaxf(m, v);
    }
    float sum = 0.f;
    for (int d = 0; d < C; ++d) { const float e = expf(row[d] - m); row[d] = e; sum += e; }
    const float inv = 1.f / sum;
    for (int d = 0; d < C; ++d) A[t * C + d] = row[d] * inv;
  }
  __syncthreads();
  for (int idx = t; idx < C * C; idx += 64) {
    const int e = idx / C, d = idx % C;
    float acc = 0.f;
    for (int cc = 0; cc < C; ++cc) acc = fmaf(proj_w[e * C + cc], A[cc * C + d], acc);
    MT[(size_t)bb * C * C + d * C + e] = acc;
  }
}

// A4: out[e,p] = sum_d MT[d,e]*v[d,p], in place on d_out. 128-px tile
// (24 KB -> 6 blocks/CU), 2 px/thread, MT rows via wave-uniform s_load.
__global__ __launch_bounds__(256) void a4_apply(
    float* __restrict__ out, const float* __restrict__ MT) {
  __shared__ float vs[C * 128];  // 24 KB
  const int t = threadIdx.x;
  const int bb = blockIdx.x >> 9;                // 512 tiles per batch
  const int p0 = (blockIdx.x & 511) << 7;        // 128 px per tile
  float* ob = out + (size_t)bb * C * HW + p0;
#pragma unroll
  for (int j = 0; j < 6; ++j) {                  // 1536 float4 = 48x128
    const int f = t + j * 256;
    const int d = f >> 5, p4 = (f & 31) * 4;
    *(float4*)&vs[d * 128 + p4] = *(const float4*)&ob[(size_t)d * HW + p4];
  }
  __syncthreads();
  const int pl = (t & 63) * 2;
  const int e0 = __builtin_amdgcn_readfirstlane((t >> 6) * 12);
  const float* mb = MT + (size_t)bb * C * C + e0;  // uniform -> s_load
  float acc[12][2];
#pragma unroll
  for (int o = 0; o < 12; ++o)
#pragma unroll
    for (int p = 0; p < 2; ++p) acc[o][p] = 0.f;
#pragma unroll 4
  for (int d = 0; d < C; ++d) {
    const float2 xv = *(const float2*)&vs[d * 128 + pl];
    const float xa[2] = {xv.x, xv.y};
#pragma unroll
    for (int jj = 0; jj < 3; ++jj) {
      const float4 wv = *(const float4*)&mb[d * C + jj * 4];
      const float wa[4] = {wv.x, wv.y, wv.z, wv.w};
#pragma unroll
      for (int o = 0; o < 4; ++o)
#pragma unroll
        for (int p = 0; p < 2; ++p)
          acc[jj * 4 + o][p] = fmaf(wa[o], xa[p], acc[jj * 4 + o][p]);
    }
  }
#pragma unroll
  for (int o = 0; o < 12; ++o) {
    float2 v;
    v.x = acc[o][0]; v.y = acc[o][1];
    *(float2*)&ob[(size_t)(e0 + o) * HW + pl] = v;
  }
}

// ==================== PATH B (fallback) kernels ==============================

__global__ __launch_bounds__(256) void k0_zero(float* __restrict__ ws) {
  const int i = blockIdx.x * 256 + threadIdx.x;
  if (i < B_ZERO_N) ws[i] = 0.f;
}

#define TS 14
#define HS 16
#define NT 19
#define NPIX 196

__global__ __launch_bounds__(256) void k1_fused(
    const float* __restrict__ x, const float* __restrict__ w1,
    const float* __restrict__ w9, float* __restrict__ vout,
    float* __restrict__ S, float* __restrict__ nq, float* __restrict__ nk) {
  __shared__ float qs[4 * 256];
  __shared__ float qt[NPIX * C];
  __shared__ float kt[NPIX * C];
  const int t = threadIdx.x;
  const int bb = blockIdx.x / (NT * NT);
  const int tile = blockIdx.x % (NT * NT);
  const int ty = tile / NT, tx = tile % NT;
  const int hy = ty * TS - 1 + (t >> 4);
  const int hx = tx * TS - 1 + (t & 15);
  const bool hin = (hy >= 0 && hy < H && hx >= 0 && hx < W);
  const float* xb = x + (size_t)bb * C * HW;
  float xv[C];
#pragma unroll
  for (int ic = 0; ic < C; ++ic)
    xv[ic] = hin ? xb[(size_t)ic * HW + hy * W + hx] : 0.f;
  const int py = t / TS, px = t % TS;
  const int gy = ty * TS + py, gx = tx * TS + px;
  const bool pin = (t < NPIX) && (gy < H) && (gx < W);
  for (int grp = 0; grp < 36; ++grp) {
    const int ch0 = grp * 4;
    const float* wp = w1 + ch0 * C;
    float a0 = 0.f, a1 = 0.f, a2 = 0.f, a3 = 0.f;
#pragma unroll
    for (int ic = 0; ic < C; ++ic) {
      const float xs = xv[ic];
      a0 = fmaf(wp[ic], xs, a0);
      a1 = fmaf(wp[C + ic], xs, a1);
      a2 = fmaf(wp[2 * C + ic], xs, a2);
      a3 = fmaf(wp[3 * C + ic], xs, a3);
    }
    qs[0 * 256 + t] = a0;
    qs[1 * 256 + t] = a1;
    qs[2 * 256 + t] = a2;
    qs[3 * 256 + t] = a3;
    __syncthreads();
    if (t < NPIX) {
#pragma unroll
      for (int g = 0; g < 4; ++g) {
        const int ch = ch0 + g;
        const float* w9p = w9 + ch * 9;
        const float* q = qs + g * 256 + py * HS + px;
        float d = w9p[0] * q[0] + w9p[1] * q[1] + w9p[2] * q[2];
        d = fmaf(w9p[3], q[HS], d);
        d = fmaf(w9p[4], q[HS + 1], d);
        d = fmaf(w9p[5], q[HS + 2], d);
        d = fmaf(w9p[6], q[2 * HS], d);
        d = fmaf(w9p[7], q[2 * HS + 1], d);
        d = fmaf(w9p[8], q[2 * HS + 2], d);
        if (ch < C)          qt[t * C + ch] = pin ? d : 0.f;
        else if (ch < 2 * C) kt[t * C + (ch - C)] = pin ? d : 0.f;
        else if (pin)        vout[((size_t)bb * C + (ch - 2 * C)) * HW + gy * W + gx] = d;
      }
    }
    __syncthreads();
  }
  if (t < C) {
    float s = 0.f;
    for (int p = 0; p < NPIX; ++p) { const float v = qt[p * C + t]; s = fmaf(v, v, s); }
    atomicAdd(&nq[bb * C + t], s);
  } else if (t >= 64 && t < 64 + C) {
    const int c = t - 64;
    float s = 0.f;
    for (int p = 0; p < NPIX; ++p) { const float v = kt[p * C + c]; s = fmaf(v, v, s); }
    atomicAdd(&nk[bb * C + c], s);
  }
  {
    const int part = t >> 6;
    const int idx = t & 63;
    const int c0 = (idx >> 3) * 6;
    const int d0 = (idx & 7) * 6;
    float acc[6][6] = {{0.f}};
    const int p0 = part * 49;
    for (int p = p0; p < p0 + 49; ++p) {
      float qv[6], kv[6];
#pragma unroll
      for (int j = 0; j < 6; ++j) { qv[j] = qt[p * C + c0 + j]; kv[j] = kt[p * C + d0 + j]; }
#pragma unroll
      for (int i = 0; i < 6; ++i)
#pragma unroll
        for (int j = 0; j < 6; ++j) acc[i][j] = fmaf(qv[i], kv[j], acc[i][j]);
    }
    float* Sb = S + (size_t)bb * C * C;
#pragma unroll
    for (int i = 0; i < 6; ++i)
#pragma unroll
      for (int j = 0; j < 6; ++j) atomicAdd(&Sb[(c0 + i) * C + (d0 + j)], acc[i][j]);
  }
}

// =============================================================================

extern "C" void kernel_launch(void* const* d_in, const int* in_sizes, int n_in,
                              void* d_out, int out_size, void* d_ws, size_t ws_size,
                              hipStream_t stream) {
  const float* x      = (const float*)d_in[0];
  const float* qkv_w  = (const float*)d_in[1];
  const float* dw_w   = (const float*)d_in[2];
  const float* proj_w = (const float*)d_in[3];
  const float* temp   = (const float*)d_in[4];
  float* out = (float*)d_out;
  float* ws  = (float*)d_ws;

  if (ws_size >= S_FLOATS * sizeof(float)) {
    float* qkv = ws + S_QKV_OFF;
    float* Sp  = ws + S_SP_OFF;
    float* nqp = ws + S_NQP_OFF;
    float* nkp = ws + S_NKP_OFF;
    float* S   = ws + S_S_OFF;
    float* nq  = ws + S_NQ_OFF;
    float* nk  = ws + S_NK_OFF;
    float* MT  = ws + S_M_OFF;
    float* wT  = ws + S_WT_OFF;
    s_wt<<<(C3 * C + 255) / 256, 256, 0, stream>>>(qkv_w, wT);
    s_conv1x1<<<B * 512, 256, 0, stream>>>(x, wT, qkv);
    s_dwgram<<<B * 256, 256, 0, stream>>>(qkv, dw_w, out, Sp, nqp, nkp);
    a3a_reduce<<<(RED_N + 255) / 256, 256, 0, stream>>>(Sp, nqp, nkp, S, nq, nk, NCH2);
    a3b_attn<<<B, 64, 0, stream>>>(S, nq, nk, proj_w, temp, MT);
    a4_apply<<<B * 512, 256, 0, stream>>>(out, MT);
  } else if (ws_size >= A_FLOATS * sizeof(float)) {
    float* dwq = ws + A_DWQ_OFF;
    float* dwk = ws + A_DWK_OFF;
    float* Sp  = ws + A_SP_OFF;
    float* nqp = ws + A_NQP_OFF;
    float* nkp = ws + A_NKP_OFF;
    float* S   = ws + A_S_OFF;
    float* nq  = ws + A_NQ_OFF;
    float* nk  = ws + A_NK_OFF;
    float* MT  = ws + A_M_OFF;
    a1_conv_dw<<<B * NTX * NTY, 256, 0, stream>>>(x, qkv_w, dw_w, dwq, dwk, out);
    a2_gram<<<B * NCHUNK, 256, 0, stream>>>(dwq, dwk, Sp, nqp, nkp);
    a3a_reduce<<<(RED_N + 255) / 256, 256, 0, stream>>>(Sp, nqp, nkp, S, nq, nk, NCHUNK);
    a3b_attn<<<B, 64, 0, stream>>>(S, nq, nk, proj_w, temp, MT);
    a4_apply<<<B * 512, 256, 0, stream>>>(out, MT);
  } else {
    float* S  = ws + B_S_OFF;
    float* nq = ws + B_NQ_OFF;
    float* nk = ws + B_NK_OFF;
    float* MT = ws + B_M_OFF;
    k0_zero<<<(B_ZERO_N + 255) / 256, 256, 0, stream>>>(ws);
    k1_fused<<<B * NT * NT, 256, 0, stream>>>(x, qkv_w, dw_w, out, S, nq, nk);
    a3b_attn<<<B, 64, 0, stream>>>(S, nq, nk, proj_w, temp, MT);
    a4_apply<<<B * 512, 256, 0, stream>>>(out, MT);
  }
}

// Round 6
// 383.554 us; speedup vs baseline: 1.4017x; 1.4017x over previous
//
#include <hip/hip_runtime.h>

#define B 4
#define C 48
#define C3 144
#define H 256
#define W 256
#define HW 65536
#define EPSN 1e-12f

// ---- a1 tiling (Path A fallback) ----
#define TSX 16
#define TSY 12
#define HSX 18
#define HSY 14
#define NTX 16
#define NTY 22
#define NPIX2 192
#define NHALO 252

#define NCHUNK 128       // gram chunks per batch
#define CHUNK 512        // pixels per gram chunk
#define LP 68            // a2 LDS stride (checked: k-reads 2-addr/bank already)

// Round-12: round-5's dw+gram fusion (direct-global stencil) was latency death
// (1.05 TB/s, 326 us) -- reverted to the round-4 structure. This round:
// (1) s_dw rewritten: float4 staging (9 VMEM/thread vs 34 scalar), DWR=32
//     (half the blocks/tails, halo 12.5->6.25%), window reads = 1 aligned
//     ds_read_b128 per row + __shfl for x-1/x+4 edges (kills the b64
//     stride-16 bank conflicts, LDS reads 6->3 per quad, all conflict-free).
// (2) a3a+a3b merged (one launch fewer, no S/nq/nk round trip), bitwise-same
//     summation orders.
#define S_QKV_OFF  ((size_t)0)
#define S_DWQ_OFF  (S_QKV_OFF + (size_t)B * C3 * HW)
#define S_DWK_OFF  (S_DWQ_OFF + (size_t)B * C * HW)
#define S_SP_OFF   (S_DWK_OFF + (size_t)B * C * HW)
#define S_NQP_OFF  (S_SP_OFF + (size_t)B * NCHUNK * C * C)
#define S_NKP_OFF  (S_NQP_OFF + (size_t)B * NCHUNK * C)
#define S_S_OFF    (S_NKP_OFF + (size_t)B * NCHUNK * C)
#define S_NQ_OFF   (S_S_OFF + (size_t)B * C * C)
#define S_NK_OFF   (S_NQ_OFF + (size_t)B * C)
#define S_M_OFF    (S_NK_OFF + (size_t)B * C)
#define S_WT_OFF   (S_M_OFF + (size_t)B * C * C)
#define S_FLOATS   (S_WT_OFF + (size_t)C3 * C)

// ================= PATH A workspace layout (floats), ~106 MB =================
#define A_DWQ_OFF  ((size_t)0)
#define A_DWK_OFF  (A_DWQ_OFF + (size_t)B * C * HW)
#define A_SP_OFF   (A_DWK_OFF + (size_t)B * C * HW)
#define A_NQP_OFF  (A_SP_OFF + (size_t)B * NCHUNK * C * C)
#define A_NKP_OFF  (A_NQP_OFF + (size_t)B * NCHUNK * C)
#define A_S_OFF    (A_NKP_OFF + (size_t)B * NCHUNK * C)
#define A_NQ_OFF   (A_S_OFF + (size_t)B * C * C)
#define A_NK_OFF   (A_NQ_OFF + (size_t)B * C)
#define A_M_OFF    (A_NK_OFF + (size_t)B * C)
#define A_FLOATS   (A_M_OFF + (size_t)B * C * C)

// ================= PATH B (fallback) workspace layout, ~75 KB ================
#define B_S_OFF  0
#define B_NQ_OFF (B * C * C)
#define B_NK_OFF (B_NQ_OFF + B * C)
#define B_M_OFF  (B_NK_OFF + B * C)
#define B_ZERO_N (B * C * C + 2 * B * C)

// ============================ PATH S kernels =================================

// S0: transpose qkv 1x1 weights [144][48] -> wT [48][144].
__global__ __launch_bounds__(256) void s_wt(
    const float* __restrict__ w1, float* __restrict__ wT) {
  const int i = blockIdx.x * 256 + threadIdx.x;
  if (i < C3 * C) {
    const int oc = i / C, d = i - oc * C;
    wT[d * C3 + oc] = w1[i];
  }
}

// S1: 1x1 conv as GEMM. 128-px tile (24 KB LDS -> 6 blocks/CU), thread owns
// 2 px, wave owns 12 oc x 3 groups; weights via wave-uniform s_load.
__global__ __launch_bounds__(256) void s_conv1x1(
    const float* __restrict__ x, const float* __restrict__ wT,
    float* __restrict__ qkv) {
  __shared__ float xs[C * 128];      // 24 KB
  const int t = threadIdx.x;
  const int bb = blockIdx.x >> 9;                // 512 pixel-tiles per batch
  const int p0 = (blockIdx.x & 511) << 7;        // 128 px per tile
  const float* xb = x + (size_t)bb * C * HW + p0;
#pragma unroll
  for (int j = 0; j < 6; ++j) {                  // 1536 float4 = 48x128
    const int f = t + j * 256;
    const int d = f >> 5, p4 = (f & 31) * 4;
    *(float4*)&xs[d * 128 + p4] = *(const float4*)&xb[(size_t)d * HW + p4];
  }
  __syncthreads();
  const int pl = (t & 63) * 2;                   // this thread's 2 pixels
  const int ocw = __builtin_amdgcn_readfirstlane((t >> 6) * 12);
#pragma unroll 1
  for (int g = 0; g < 3; ++g) {
    const int oc0 = g * 48 + ocw;                // provably wave-uniform
    const float* wp = wT + oc0;                  // uniform -> s_load base
    float acc[12][2];
#pragma unroll
    for (int o = 0; o < 12; ++o)
#pragma unroll
      for (int p = 0; p < 2; ++p) acc[o][p] = 0.f;
#pragma unroll 4
    for (int d = 0; d < C; ++d) {
      const float2 xv = *(const float2*)&xs[d * 128 + pl];
      const float xa[2] = {xv.x, xv.y};
#pragma unroll
      for (int jj = 0; jj < 3; ++jj) {
        const float4 wv = *(const float4*)&wp[d * C3 + jj * 4];
        const float wa[4] = {wv.x, wv.y, wv.z, wv.w};
#pragma unroll
        for (int o = 0; o < 4; ++o)
#pragma unroll
          for (int p = 0; p < 2; ++p)
            acc[jj * 4 + o][p] = fmaf(wa[o], xa[p], acc[jj * 4 + o][p]);
      }
    }
    float* ob = qkv + ((size_t)bb * C3 + oc0) * HW + p0 + pl;
#pragma unroll
    for (int o = 0; o < 12; ++o) {
      float2 v;
      v.x = acc[o][0]; v.y = acc[o][1];
      *(float2*)&ob[(size_t)o * HW] = v;
    }
  }
}

// S2: depthwise 3x3, streaming. Round-12: block = (batch, channel, 32-row
// band). Staging: 34 rows x 256 cols, natural layout, float4 loads (9 VMEM
// per thread). Window reads: one aligned ds_read_b128 per row (conflict-free)
// + __shfl_up/down for the x-1 / x+4 edge elements (DPP, off the LDS pipe).
// FMA expression structure identical to round-4 -> bitwise-same outputs.
#define DWR 32
#define DWROWS (DWR + 2)   // 34
__global__ __launch_bounds__(256) void s_dw(
    const float* __restrict__ qkv, const float* __restrict__ w9,
    float* __restrict__ dwq, float* __restrict__ dwk,
    float* __restrict__ vout) {
  __shared__ float ls[DWROWS * 256];   // 34,816 B -> 4 blocks/CU
  const int t = threadIdx.x;
  const int rblk = blockIdx.x & 7;               // 8 bands of 32 rows
  const int cb = blockIdx.x >> 3;                // bb*144 + c
  const int c = cb % C3;
  const int bb = cb / C3;
  const int r0 = rblk * DWR;
  const float* src = qkv + (size_t)cb * HW;
#pragma unroll
  for (int i = 0; i < 9; ++i) {                  // 2176 float4 = 34x64
    const int f4 = t + i * 256;
    if (f4 < DWROWS * 64) {
      const int rr = f4 >> 6, c4 = (f4 & 63) * 4;
      const int gr = r0 - 1 + rr;
      float4 v = make_float4(0.f, 0.f, 0.f, 0.f);
      if (gr >= 0 && gr < H) v = *(const float4*)&src[gr * W + c4];
      *(float4*)&ls[rr * 256 + c4] = v;
    }
  }
  const float* wp = w9 + c * 9;                  // uniform -> s_load
  float wv[9];
#pragma unroll
  for (int k = 0; k < 9; ++k) wv[k] = wp[k];
  __syncthreads();
  float* dst;
  int cc;
  if (c < C)          { dst = dwq;  cc = c; }
  else if (c < 2 * C) { dst = dwk;  cc = c - C; }
  else                { dst = vout; cc = c - 2 * C; }
  float* ob = dst + ((size_t)bb * C + cc) * HW;
  const int lane = t & 63;
  const int xq = lane * 4;                       // 4 output cols per thread
  const int rw = t >> 6;                         // wave owns every 4th row
#pragma unroll
  for (int rr = rw; rr < DWR; rr += 4) {
    // output row r0+rr uses ls rows rr, rr+1, rr+2 (ls row 0 = global r0-1)
    const float4 a0 = *(const float4*)&ls[(rr + 0) * 256 + xq];
    const float4 a1 = *(const float4*)&ls[(rr + 1) * 256 + xq];
    const float4 a2 = *(const float4*)&ls[(rr + 2) * 256 + xq];
    float vm0 = __shfl_up(a0.w, 1);  // col xq-1 from left neighbor lane
    float vm1 = __shfl_up(a1.w, 1);
    float vm2 = __shfl_up(a2.w, 1);
    float vp0 = __shfl_down(a0.x, 1);  // col xq+4 from right neighbor lane
    float vp1 = __shfl_down(a1.x, 1);
    float vp2 = __shfl_down(a2.x, 1);
    if (lane == 0)  { vm0 = 0.f; vm1 = 0.f; vm2 = 0.f; }   // x==0 boundary
    if (lane == 63) { vp0 = 0.f; vp1 = 0.f; vp2 = 0.f; }   // x==255 boundary
    const float r0e[6] = {vm0, a0.x, a0.y, a0.z, a0.w, vp0};
    const float r1e[6] = {vm1, a1.x, a1.y, a1.z, a1.w, vp1};
    const float r2e[6] = {vm2, a2.x, a2.y, a2.z, a2.w, vp2};
    float4 o;
    float* op = &o.x;
#pragma unroll
    for (int j = 0; j < 4; ++j) {
      float d = wv[0] * r0e[j] + wv[1] * r0e[j + 1] + wv[2] * r0e[j + 2];
      d = fmaf(wv[3], r1e[j], d);
      d = fmaf(wv[4], r1e[j + 1], d);
      d = fmaf(wv[5], r1e[j + 2], d);
      d = fmaf(wv[6], r2e[j], d);
      d = fmaf(wv[7], r2e[j + 1], d);
      d = fmaf(wv[8], r2e[j + 2], d);
      op[j] = d;
    }
    *(float4*)&ob[(r0 + rr) * W + xq] = o;
  }
}

// ============================ PATH A kernels =================================

// A1: 1x1 conv + depthwise 3x3 fused (fallback path only).
__global__ __launch_bounds__(256) void a1_conv_dw(
    const float* __restrict__ x, const float* __restrict__ w1,
    const float* __restrict__ w9, float* __restrict__ dwq,
    float* __restrict__ dwk, float* __restrict__ vout) {
  __shared__ float xs[C * 256];
  __shared__ float qs[8 * 256];
  __shared__ float wg[C * 8];
  __shared__ float wg9[8 * 9];
  const int t = threadIdx.x;
  const int bb = blockIdx.x / (NTX * NTY);
  const int tile = blockIdx.x % (NTX * NTY);
  const int ty = tile / NTX, tx = tile % NTX;
  const int hyy = t / HSX, hxx = t % HSX;
  const int hy = ty * TSY - 1 + hyy;
  const int hx = tx * TSX - 1 + hxx;
  const bool hin = (t < NHALO) && (hy >= 0) && (hy < H) && (hx >= 0) && (hx < W);
  const float* xb = x + (size_t)bb * C * HW + (hin ? (hy * W + hx) : 0);
#pragma unroll
  for (int ic = 0; ic < C; ++ic)
    xs[ic * 256 + t] = hin ? xb[(size_t)ic * HW] : 0.f;
  const int py = t / TSX, px = t % TSX;
  const int gy = ty * TSY + py, gx = tx * TSX + px;
  const bool pin = (t < NPIX2) && (gy < H);
  const int hpos = py * HSX + px;
  for (int grp = 0; grp < 18; ++grp) {
    const int ch0 = grp * 8;
    {
      const int j = t + ((t < 128) ? 256 : 0);
      if (t < 128) {
        const int ic = t >> 3, g = t & 7;
        wg[t] = w1[(ch0 + g) * C + ic];
        const int ic2 = j >> 3, g2 = j & 7;
        wg[j] = w1[(ch0 + g2) * C + ic2];
      } else if (t < 256) {
        const int r = t - 128;
        const int ic = (r + 128) >> 3, g = (r + 128) & 7;
        wg[r + 128] = w1[(ch0 + g) * C + ic];
      }
      if (t < 72) wg9[t] = w9[ch0 * 9 + t];
    }
    __syncthreads();
    float a[8];
#pragma unroll
    for (int g = 0; g < 8; ++g) a[g] = 0.f;
#pragma unroll 4
    for (int ic = 0; ic < C; ++ic) {
      const float xsv = xs[ic * 256 + t];
      const float4 w0 = *(const float4*)&wg[ic * 8];
      const float4 w4 = *(const float4*)&wg[ic * 8 + 4];
      a[0] = fmaf(w0.x, xsv, a[0]);
      a[1] = fmaf(w0.y, xsv, a[1]);
      a[2] = fmaf(w0.z, xsv, a[2]);
      a[3] = fmaf(w0.w, xsv, a[3]);
      a[4] = fmaf(w4.x, xsv, a[4]);
      a[5] = fmaf(w4.y, xsv, a[5]);
      a[6] = fmaf(w4.z, xsv, a[6]);
      a[7] = fmaf(w4.w, xsv, a[7]);
    }
#pragma unroll
    for (int g = 0; g < 8; ++g) qs[g * 256 + t] = a[g];
    __syncthreads();
    if (t < NPIX2) {
#pragma unroll
      for (int g = 0; g < 8; ++g) {
        const int ch = ch0 + g;
        const float* w9p = wg9 + g * 9;
        const float* q = qs + g * 256 + hpos;
        float d = w9p[0] * q[0] + w9p[1] * q[1] + w9p[2] * q[2];
        d = fmaf(w9p[3], q[HSX], d);
        d = fmaf(w9p[4], q[HSX + 1], d);
        d = fmaf(w9p[5], q[HSX + 2], d);
        d = fmaf(w9p[6], q[2 * HSX], d);
        d = fmaf(w9p[7], q[2 * HSX + 1], d);
        d = fmaf(w9p[8], q[2 * HSX + 2], d);
        if (pin) {
          float* dst;
          int cc;
          if (ch < C)          { dst = dwq; cc = ch; }
          else if (ch < 2 * C) { dst = dwk; cc = ch - C; }
          else                 { dst = vout; cc = ch - 2 * C; }
          dst[((size_t)bb * C + cc) * HW + gy * W + gx] = d;
        }
      }
    }
    __syncthreads();
  }
}

// A2: per-chunk Gram partials + norm partials, register double-buffered (T14).
__global__ __launch_bounds__(256) void a2_gram(
    const float* __restrict__ dwq, const float* __restrict__ dwk,
    float* __restrict__ Sp, float* __restrict__ nqp, float* __restrict__ nkp) {
  __shared__ float qs[C * LP];
  __shared__ float ks[C * LP];
  const int tid = threadIdx.x;
  const int bb = blockIdx.x / NCHUNK;
  const int chunk = blockIdx.x % NCHUNK;
  const int base = chunk * CHUNK;
  const float* qb = dwq + (size_t)bb * C * HW + base;
  const float* kb = dwk + (size_t)bb * C * HW + base;
  const int c0 = (tid >> 4) * 3;
  const int d0 = (tid & 15) * 3;
  float acc[3][3] = {{0.f}};
  float nacc = 0.f;
  float4 rq[3], rk[3];
#pragma unroll
  for (int j = 0; j < 3; ++j) {
    const int f = tid + j * 256;
    const int cc = f >> 4, p4 = (f & 15) * 4;
    rq[j] = *(const float4*)&qb[(size_t)cc * HW + p4];
    rk[j] = *(const float4*)&kb[(size_t)cc * HW + p4];
  }
  for (int sub = 0; sub < CHUNK / 64; ++sub) {
    __syncthreads();
#pragma unroll
    for (int j = 0; j < 3; ++j) {
      const int f = tid + j * 256;
      const int cc = f >> 4, p4 = (f & 15) * 4;
      *(float4*)&qs[cc * LP + p4] = rq[j];
      *(float4*)&ks[cc * LP + p4] = rk[j];
    }
    if (sub < CHUNK / 64 - 1) {
#pragma unroll
      for (int j = 0; j < 3; ++j) {
        const int f = tid + j * 256;
        const int cc = f >> 4, p4 = (f & 15) * 4;
        rq[j] = *(const float4*)&qb[(size_t)cc * HW + (sub + 1) * 64 + p4];
        rk[j] = *(const float4*)&kb[(size_t)cc * HW + (sub + 1) * 64 + p4];
      }
    }
    __syncthreads();
    if (tid < C) {
#pragma unroll
      for (int pq = 0; pq < 64; pq += 4) {
        const float4 v = *(const float4*)&qs[tid * LP + pq];
        nacc = fmaf(v.x, v.x, nacc);
        nacc = fmaf(v.y, v.y, nacc);
        nacc = fmaf(v.z, v.z, nacc);
        nacc = fmaf(v.w, v.w, nacc);
      }
    } else if (tid >= 64 && tid < 64 + C) {
      const int cq = tid - 64;
#pragma unroll
      for (int pq = 0; pq < 64; pq += 4) {
        const float4 v = *(const float4*)&ks[cq * LP + pq];
        nacc = fmaf(v.x, v.x, nacc);
        nacc = fmaf(v.y, v.y, nacc);
        nacc = fmaf(v.z, v.z, nacc);
        nacc = fmaf(v.w, v.w, nacc);
      }
    }
#pragma unroll 4
    for (int pq = 0; pq < 64; pq += 4) {
      const float4 q0 = *(const float4*)&qs[(c0 + 0) * LP + pq];
      const float4 q1 = *(const float4*)&qs[(c0 + 1) * LP + pq];
      const float4 q2 = *(const float4*)&qs[(c0 + 2) * LP + pq];
      const float4 k0 = *(const float4*)&ks[(d0 + 0) * LP + pq];
      const float4 k1 = *(const float4*)&ks[(d0 + 1) * LP + pq];
      const float4 k2 = *(const float4*)&ks[(d0 + 2) * LP + pq];
      const float qa[3][4] = {{q0.x, q0.y, q0.z, q0.w},
                              {q1.x, q1.y, q1.z, q1.w},
                              {q2.x, q2.y, q2.z, q2.w}};
      const float ka[3][4] = {{k0.x, k0.y, k0.z, k0.w},
                              {k1.x, k1.y, k1.z, k1.w},
                              {k2.x, k2.y, k2.z, k2.w}};
#pragma unroll
      for (int p = 0; p < 4; ++p)
#pragma unroll
        for (int i = 0; i < 3; ++i)
#pragma unroll
          for (int j = 0; j < 3; ++j)
            acc[i][j] = fmaf(qa[i][p], ka[j][p], acc[i][j]);
    }
  }
  float* Sb = Sp + ((size_t)bb * NCHUNK + chunk) * C * C;
#pragma unroll
  for (int i = 0; i < 3; ++i)
#pragma unroll
    for (int j = 0; j < 3; ++j)
      Sb[(c0 + i) * C + (d0 + j)] = acc[i][j];
  if (tid < C)                        nqp[((size_t)bb * NCHUNK + chunk) * C + tid] = nacc;
  else if (tid >= 64 && tid < 64 + C) nkp[((size_t)bb * NCHUNK + chunk) * C + (tid - 64)] = nacc;
}

// A3 (merged): reduce chunk partials + normalize + softmax + fold proj.
// One 256-thread block per batch. Same summation orders as the old
// a3a_reduce/a3b_attn pair -> bitwise-identical MT.
__global__ __launch_bounds__(256) void a3_merged(
    const float* __restrict__ Sp, const float* __restrict__ nqp,
    const float* __restrict__ nkp, const float* __restrict__ proj_w,
    const float* __restrict__ temperature, float* __restrict__ MT,
    int nchunk) {
  __shared__ float Sl[C * C];
  __shared__ float A[C * C];
  __shared__ float qnl[C];
  __shared__ float knl[C];
  const int bb = blockIdx.x;
  const int t = threadIdx.x;
  const float T = temperature[0];
  for (int j = t; j < C * C; j += 256) {         // 9 outputs per thread
    const float* src = Sp + (size_t)bb * nchunk * C * C + j;
    float s = 0.f;
#pragma unroll 8
    for (int i = 0; i < nchunk; ++i) s += src[(size_t)i * C * C];
    Sl[j] = s;
  }
  if (t < C) {
    const float* src = nqp + (size_t)bb * nchunk * C + t;
    float s = 0.f;
#pragma unroll 8
    for (int i = 0; i < nchunk; ++i) s += src[(size_t)i * C];
    qnl[t] = fmaxf(sqrtf(s), EPSN);
  } else if (t >= 64 && t < 64 + C) {
    const float* src = nkp + (size_t)bb * nchunk * C + (t - 64);
    float s = 0.f;
#pragma unroll 8
    for (int i = 0; i < nchunk; ++i) s += src[(size_t)i * C];
    knl[t - 64] = fmaxf(sqrtf(s), EPSN);
  }
  __syncthreads();
  if (t < C) {
    const float qn = qnl[t];
    float row[C];
    float m = -1e30f;
    for (int d = 0; d < C; ++d) {
      const float v = Sl[t * C + d] / (qn * knl[d]) * T;
      row[d] = v;
      m = fmaxf(m, v);
    }
    float sum = 0.f;
    for (int d = 0; d < C; ++d) { const float e = expf(row[d] - m); row[d] = e; sum += e; }
    const float inv = 1.f / sum;
    for (int d = 0; d < C; ++d) A[t * C + d] = row[d] * inv;
  }
  __syncthreads();
  for (int idx = t; idx < C * C; idx += 256) {
    const int e = idx / C, d = idx % C;
    float acc = 0.f;
    for (int cc = 0; cc < C; ++cc) acc = fmaf(proj_w[e * C + cc], A[cc * C + d], acc);
    MT[(size_t)bb * C * C + d * C + e] = acc;
  }
}

// A3b (Path B only): normalize S, softmax rows, fold proj; writes MT.
__global__ __launch_bounds__(64) void a3b_attn(
    const float* __restrict__ S, const float* __restrict__ nq,
    const float* __restrict__ nk, const float* __restrict__ proj_w,
    const float* __restrict__ temperature, float* __restrict__ MT) {
  __shared__ float A[C * C];
  __shared__ float knl[C];
  const int bb = blockIdx.x;
  const int t = threadIdx.x;
  const float T = temperature[0];
  if (t < C) knl[t] = fmaxf(sqrtf(nk[bb * C + t]), EPSN);
  __syncthreads();
  if (t < C) {
    const float qn = fmaxf(sqrtf(nq[bb * C + t]), EPSN);
    float row[C];
    float m = -1e30f;
    for (int d = 0; d < C; ++d) {
      const float v = S[(size_t)bb * C * C + t * C + d] / (qn * knl[d]) * T;
      row[d] = v;
      m = fmaxf(m, v);
    }
    float sum = 0.f;
    for (int d = 0; d < C; ++d) { const float e = expf(row[d] - m); row[d] = e; sum += e; }
    const float inv = 1.f / sum;
    for (int d = 0; d < C; ++d) A[t * C + d] = row[d] * inv;
  }
  __syncthreads();
  for (int idx = t; idx < C * C; idx += 64) {
    const int e = idx / C, d = idx % C;
    float acc = 0.f;
    for (int cc = 0; cc < C; ++cc) acc = fmaf(proj_w[e * C + cc], A[cc * C + d], acc);
    MT[(size_t)bb * C * C + d * C + e] = acc;
  }
}

// A4: out[e,p] = sum_d MT[d,e]*v[d,p], in place on d_out. 128-px tile
// (24 KB -> 6 blocks/CU), 2 px/thread, MT rows via wave-uniform s_load.
__global__ __launch_bounds__(256) void a4_apply(
    float* __restrict__ out, const float* __restrict__ MT) {
  __shared__ float vs[C * 128];  // 24 KB
  const int t = threadIdx.x;
  const int bb = blockIdx.x >> 9;                // 512 tiles per batch
  const int p0 = (blockIdx.x & 511) << 7;        // 128 px per tile
  float* ob = out + (size_t)bb * C * HW + p0;
#pragma unroll
  for (int j = 0; j < 6; ++j) {                  // 1536 float4 = 48x128
    const int f = t + j * 256;
    const int d = f >> 5, p4 = (f & 31) * 4;
    *(float4*)&vs[d * 128 + p4] = *(const float4*)&ob[(size_t)d * HW + p4];
  }
  __syncthreads();
  const int pl = (t & 63) * 2;
  const int e0 = __builtin_amdgcn_readfirstlane((t >> 6) * 12);
  const float* mb = MT + (size_t)bb * C * C + e0;  // uniform -> s_load
  float acc[12][2];
#pragma unroll
  for (int o = 0; o < 12; ++o)
#pragma unroll
    for (int p = 0; p < 2; ++p) acc[o][p] = 0.f;
#pragma unroll 4
  for (int d = 0; d < C; ++d) {
    const float2 xv = *(const float2*)&vs[d * 128 + pl];
    const float xa[2] = {xv.x, xv.y};
#pragma unroll
    for (int jj = 0; jj < 3; ++jj) {
      const float4 wv = *(const float4*)&mb[d * C + jj * 4];
      const float wa[4] = {wv.x, wv.y, wv.z, wv.w};
#pragma unroll
      for (int o = 0; o < 4; ++o)
#pragma unroll
        for (int p = 0; p < 2; ++p)
          acc[jj * 4 + o][p] = fmaf(wa[o], xa[p], acc[jj * 4 + o][p]);
    }
  }
#pragma unroll
  for (int o = 0; o < 12; ++o) {
    float2 v;
    v.x = acc[o][0]; v.y = acc[o][1];
    *(float2*)&ob[(size_t)(e0 + o) * HW + pl] = v;
  }
}

// ==================== PATH B (fallback) kernels ==============================

__global__ __launch_bounds__(256) void k0_zero(float* __restrict__ ws) {
  const int i = blockIdx.x * 256 + threadIdx.x;
  if (i < B_ZERO_N) ws[i] = 0.f;
}

#define TS 14
#define HS 16
#define NT 19
#define NPIX 196

__global__ __launch_bounds__(256) void k1_fused(
    const float* __restrict__ x, const float* __restrict__ w1,
    const float* __restrict__ w9, float* __restrict__ vout,
    float* __restrict__ S, float* __restrict__ nq, float* __restrict__ nk) {
  __shared__ float qs[4 * 256];
  __shared__ float qt[NPIX * C];
  __shared__ float kt[NPIX * C];
  const int t = threadIdx.x;
  const int bb = blockIdx.x / (NT * NT);
  const int tile = blockIdx.x % (NT * NT);
  const int ty = tile / NT, tx = tile % NT;
  const int hy = ty * TS - 1 + (t >> 4);
  const int hx = tx * TS - 1 + (t & 15);
  const bool hin = (hy >= 0 && hy < H && hx >= 0 && hx < W);
  const float* xb = x + (size_t)bb * C * HW;
  float xv[C];
#pragma unroll
  for (int ic = 0; ic < C; ++ic)
    xv[ic] = hin ? xb[(size_t)ic * HW + hy * W + hx] : 0.f;
  const int py = t / TS, px = t % TS;
  const int gy = ty * TS + py, gx = tx * TS + px;
  const bool pin = (t < NPIX) && (gy < H) && (gx < W);
  for (int grp = 0; grp < 36; ++grp) {
    const int ch0 = grp * 4;
    const float* wp = w1 + ch0 * C;
    float a0 = 0.f, a1 = 0.f, a2 = 0.f, a3 = 0.f;
#pragma unroll
    for (int ic = 0; ic < C; ++ic) {
      const float xs = xv[ic];
      a0 = fmaf(wp[ic], xs, a0);
      a1 = fmaf(wp[C + ic], xs, a1);
      a2 = fmaf(wp[2 * C + ic], xs, a2);
      a3 = fmaf(wp[3 * C + ic], xs, a3);
    }
    qs[0 * 256 + t] = a0;
    qs[1 * 256 + t] = a1;
    qs[2 * 256 + t] = a2;
    qs[3 * 256 + t] = a3;
    __syncthreads();
    if (t < NPIX) {
#pragma unroll
      for (int g = 0; g < 4; ++g) {
        const int ch = ch0 + g;
        const float* w9p = w9 + ch * 9;
        const float* q = qs + g * 256 + py * HS + px;
        float d = w9p[0] * q[0] + w9p[1] * q[1] + w9p[2] * q[2];
        d = fmaf(w9p[3], q[HS], d);
        d = fmaf(w9p[4], q[HS + 1], d);
        d = fmaf(w9p[5], q[HS + 2], d);
        d = fmaf(w9p[6], q[2 * HS], d);
        d = fmaf(w9p[7], q[2 * HS + 1], d);
        d = fmaf(w9p[8], q[2 * HS + 2], d);
        if (ch < C)          qt[t * C + ch] = pin ? d : 0.f;
        else if (ch < 2 * C) kt[t * C + (ch - C)] = pin ? d : 0.f;
        else if (pin)        vout[((size_t)bb * C + (ch - 2 * C)) * HW + gy * W + gx] = d;
      }
    }
    __syncthreads();
  }
  if (t < C) {
    float s = 0.f;
    for (int p = 0; p < NPIX; ++p) { const float v = qt[p * C + t]; s = fmaf(v, v, s); }
    atomicAdd(&nq[bb * C + t], s);
  } else if (t >= 64 && t < 64 + C) {
    const int c = t - 64;
    float s = 0.f;
    for (int p = 0; p < NPIX; ++p) { const float v = kt[p * C + c]; s = fmaf(v, v, s); }
    atomicAdd(&nk[bb * C + c], s);
  }
  {
    const int part = t >> 6;
    const int idx = t & 63;
    const int c0 = (idx >> 3) * 6;
    const int d0 = (idx & 7) * 6;
    float acc[6][6] = {{0.f}};
    const int p0 = part * 49;
    for (int p = p0; p < p0 + 49; ++p) {
      float qv[6], kv[6];
#pragma unroll
      for (int j = 0; j < 6; ++j) { qv[j] = qt[p * C + c0 + j]; kv[j] = kt[p * C + d0 + j]; }
#pragma unroll
      for (int i = 0; i < 6; ++i)
#pragma unroll
        for (int j = 0; j < 6; ++j) acc[i][j] = fmaf(qv[i], kv[j], acc[i][j]);
    }
    float* Sb = S + (size_t)bb * C * C;
#pragma unroll
    for (int i = 0; i < 6; ++i)
#pragma unroll
      for (int j = 0; j < 6; ++j) atomicAdd(&Sb[(c0 + i) * C + (d0 + j)], acc[i][j]);
  }
}

// =============================================================================

extern "C" void kernel_launch(void* const* d_in, const int* in_sizes, int n_in,
                              void* d_out, int out_size, void* d_ws, size_t ws_size,
                              hipStream_t stream) {
  const float* x      = (const float*)d_in[0];
  const float* qkv_w  = (const float*)d_in[1];
  const float* dw_w   = (const float*)d_in[2];
  const float* proj_w = (const float*)d_in[3];
  const float* temp   = (const float*)d_in[4];
  float* out = (float*)d_out;
  float* ws  = (float*)d_ws;

  if (ws_size >= S_FLOATS * sizeof(float)) {
    float* qkv = ws + S_QKV_OFF;
    float* dwq = ws + S_DWQ_OFF;
    float* dwk = ws + S_DWK_OFF;
    float* Sp  = ws + S_SP_OFF;
    float* nqp = ws + S_NQP_OFF;
    float* nkp = ws + S_NKP_OFF;
    float* MT  = ws + S_M_OFF;
    float* wT  = ws + S_WT_OFF;
    s_wt<<<(C3 * C + 255) / 256, 256, 0, stream>>>(qkv_w, wT);
    s_conv1x1<<<B * 512, 256, 0, stream>>>(x, wT, qkv);
    s_dw<<<B * C3 * (H / DWR), 256, 0, stream>>>(qkv, dw_w, dwq, dwk, out);
    a2_gram<<<B * NCHUNK, 256, 0, stream>>>(dwq, dwk, Sp, nqp, nkp);
    a3_merged<<<B, 256, 0, stream>>>(Sp, nqp, nkp, proj_w, temp, MT, NCHUNK);
    a4_apply<<<B * 512, 256, 0, stream>>>(out, MT);
  } else if (ws_size >= A_FLOATS * sizeof(float)) {
    float* dwq = ws + A_DWQ_OFF;
    float* dwk = ws + A_DWK_OFF;
    float* Sp  = ws + A_SP_OFF;
    float* nqp = ws + A_NQP_OFF;
    float* nkp = ws + A_NKP_OFF;
    float* MT  = ws + A_M_OFF;
    a1_conv_dw<<<B * NTX * NTY, 256, 0, stream>>>(x, qkv_w, dw_w, dwq, dwk, out);
    a2_gram<<<B * NCHUNK, 256, 0, stream>>>(dwq, dwk, Sp, nqp, nkp);
    a3_merged<<<B, 256, 0, stream>>>(Sp, nqp, nkp, proj_w, temp, MT, NCHUNK);
    a4_apply<<<B * 512, 256, 0, stream>>>(out, MT);
  } else {
    float* S  = ws + B_S_OFF;
    float* nq = ws + B_NQ_OFF;
    float* nk = ws + B_NK_OFF;
    float* MT = ws + B_M_OFF;
    k0_zero<<<(B_ZERO_N + 255) / 256, 256, 0, stream>>>(ws);
    k1_fused<<<B * NT * NT, 256, 0, stream>>>(x, qkv_w, dw_w, out, S, nq, nk);
    a3b_attn<<<B, 64, 0, stream>>>(S, nq, nk, proj_w, temp, MT);
    a4_apply<<<B * 512, 256, 0, stream>>>(out, MT);
  }
}

// Round 8
// 324.153 us; speedup vs baseline: 1.6586x; 1.1832x over previous
//
#include <hip/hip_runtime.h>

#define B 4
#define C 48
#define C3 144
#define H 256
#define W 256
#define HW 65536
#define EPSN 1e-12f

// ---- a1 tiling (Path A fallback) ----
#define TSX 16
#define TSY 12
#define HSX 18
#define HSY 14
#define NTX 16
#define NTY 22
#define NPIX2 192
#define NHALO 252

#define NCHUNK 128       // gram chunks per batch
#define CHUNK 512        // pixels per gram chunk
#define LP 68            // a2 LDS stride

// Round-14: resubmission of round-13 (pytest core-dump was an infra flake:
// every kernel + offset in that source had previously passed -- round-6 base
// kernels at 383 us, a3a/a3b verbatim from round-4's 337.8 us run). Structure:
// s_conv1x1 (128-px) -> s_dw (DWR=32, float4 staging, shfl edges) ->
// a2_gram (T14 prefetch) -> flat a3a_reduce -> a3b_attn -> a4_apply.
#define S_QKV_OFF  ((size_t)0)
#define S_DWQ_OFF  (S_QKV_OFF + (size_t)B * C3 * HW)
#define S_DWK_OFF  (S_DWQ_OFF + (size_t)B * C * HW)
#define S_SP_OFF   (S_DWK_OFF + (size_t)B * C * HW)
#define S_NQP_OFF  (S_SP_OFF + (size_t)B * NCHUNK * C * C)
#define S_NKP_OFF  (S_NQP_OFF + (size_t)B * NCHUNK * C)
#define S_S_OFF    (S_NKP_OFF + (size_t)B * NCHUNK * C)
#define S_NQ_OFF   (S_S_OFF + (size_t)B * C * C)
#define S_NK_OFF   (S_NQ_OFF + (size_t)B * C)
#define S_M_OFF    (S_NK_OFF + (size_t)B * C)
#define S_WT_OFF   (S_M_OFF + (size_t)B * C * C)
#define S_FLOATS   (S_WT_OFF + (size_t)C3 * C)

// ================= PATH A workspace layout (floats), ~106 MB =================
#define A_DWQ_OFF  ((size_t)0)
#define A_DWK_OFF  (A_DWQ_OFF + (size_t)B * C * HW)
#define A_SP_OFF   (A_DWK_OFF + (size_t)B * C * HW)
#define A_NQP_OFF  (A_SP_OFF + (size_t)B * NCHUNK * C * C)
#define A_NKP_OFF  (A_NQP_OFF + (size_t)B * NCHUNK * C)
#define A_S_OFF    (A_NKP_OFF + (size_t)B * NCHUNK * C)
#define A_NQ_OFF   (A_S_OFF + (size_t)B * C * C)
#define A_NK_OFF   (A_NQ_OFF + (size_t)B * C)
#define A_M_OFF    (A_NK_OFF + (size_t)B * C)
#define A_FLOATS   (A_M_OFF + (size_t)B * C * C)

// ================= PATH B (fallback) workspace layout, ~75 KB ================
#define B_S_OFF  0
#define B_NQ_OFF (B * C * C)
#define B_NK_OFF (B_NQ_OFF + B * C)
#define B_M_OFF  (B_NK_OFF + B * C)
#define B_ZERO_N (B * C * C + 2 * B * C)

// ============================ PATH S kernels =================================

// S0: transpose qkv 1x1 weights [144][48] -> wT [48][144].
__global__ __launch_bounds__(256) void s_wt(
    const float* __restrict__ w1, float* __restrict__ wT) {
  const int i = blockIdx.x * 256 + threadIdx.x;
  if (i < C3 * C) {
    const int oc = i / C, d = i - oc * C;
    wT[d * C3 + oc] = w1[i];
  }
}

// S1: 1x1 conv as GEMM. 128-px tile (24 KB LDS -> 6 blocks/CU), thread owns
// 2 px, wave owns 12 oc x 3 groups; weights via wave-uniform s_load.
__global__ __launch_bounds__(256) void s_conv1x1(
    const float* __restrict__ x, const float* __restrict__ wT,
    float* __restrict__ qkv) {
  __shared__ float xs[C * 128];      // 24 KB
  const int t = threadIdx.x;
  const int bb = blockIdx.x >> 9;                // 512 pixel-tiles per batch
  const int p0 = (blockIdx.x & 511) << 7;        // 128 px per tile
  const float* xb = x + (size_t)bb * C * HW + p0;
#pragma unroll
  for (int j = 0; j < 6; ++j) {                  // 1536 float4 = 48x128
    const int f = t + j * 256;
    const int d = f >> 5, p4 = (f & 31) * 4;
    *(float4*)&xs[d * 128 + p4] = *(const float4*)&xb[(size_t)d * HW + p4];
  }
  __syncthreads();
  const int pl = (t & 63) * 2;                   // this thread's 2 pixels
  const int ocw = __builtin_amdgcn_readfirstlane((t >> 6) * 12);
#pragma unroll 1
  for (int g = 0; g < 3; ++g) {
    const int oc0 = g * 48 + ocw;                // provably wave-uniform
    const float* wp = wT + oc0;                  // uniform -> s_load base
    float acc[12][2];
#pragma unroll
    for (int o = 0; o < 12; ++o)
#pragma unroll
      for (int p = 0; p < 2; ++p) acc[o][p] = 0.f;
#pragma unroll 4
    for (int d = 0; d < C; ++d) {
      const float2 xv = *(const float2*)&xs[d * 128 + pl];
      const float xa[2] = {xv.x, xv.y};
#pragma unroll
      for (int jj = 0; jj < 3; ++jj) {
        const float4 wv = *(const float4*)&wp[d * C3 + jj * 4];
        const float wa[4] = {wv.x, wv.y, wv.z, wv.w};
#pragma unroll
        for (int o = 0; o < 4; ++o)
#pragma unroll
          for (int p = 0; p < 2; ++p)
            acc[jj * 4 + o][p] = fmaf(wa[o], xa[p], acc[jj * 4 + o][p]);
      }
    }
    float* ob = qkv + ((size_t)bb * C3 + oc0) * HW + p0 + pl;
#pragma unroll
    for (int o = 0; o < 12; ++o) {
      float2 v;
      v.x = acc[o][0]; v.y = acc[o][1];
      *(float2*)&ob[(size_t)o * HW] = v;
    }
  }
}

// S2: depthwise 3x3, streaming. Block = (batch, channel, 32-row band).
// float4 staging (9 VMEM/thread), aligned ds_read_b128 window reads +
// __shfl edges (conflict-free). FMA structure = round-4 -> bitwise-same.
#define DWR 32
#define DWROWS (DWR + 2)   // 34
__global__ __launch_bounds__(256) void s_dw(
    const float* __restrict__ qkv, const float* __restrict__ w9,
    float* __restrict__ dwq, float* __restrict__ dwk,
    float* __restrict__ vout) {
  __shared__ float ls[DWROWS * 256];   // 34,816 B -> 4 blocks/CU
  const int t = threadIdx.x;
  const int rblk = blockIdx.x & 7;               // 8 bands of 32 rows
  const int cb = blockIdx.x >> 3;                // bb*144 + c
  const int c = cb % C3;
  const int bb = cb / C3;
  const int r0 = rblk * DWR;
  const float* src = qkv + (size_t)cb * HW;
#pragma unroll
  for (int i = 0; i < 9; ++i) {                  // 2176 float4 = 34x64
    const int f4 = t + i * 256;
    if (f4 < DWROWS * 64) {
      const int rr = f4 >> 6, c4 = (f4 & 63) * 4;
      const int gr = r0 - 1 + rr;
      float4 v = make_float4(0.f, 0.f, 0.f, 0.f);
      if (gr >= 0 && gr < H) v = *(const float4*)&src[gr * W + c4];
      *(float4*)&ls[rr * 256 + c4] = v;
    }
  }
  const float* wp = w9 + c * 9;                  // uniform -> s_load
  float wv[9];
#pragma unroll
  for (int k = 0; k < 9; ++k) wv[k] = wp[k];
  __syncthreads();
  float* dst;
  int cc;
  if (c < C)          { dst = dwq;  cc = c; }
  else if (c < 2 * C) { dst = dwk;  cc = c - C; }
  else                { dst = vout; cc = c - 2 * C; }
  float* ob = dst + ((size_t)bb * C + cc) * HW;
  const int lane = t & 63;
  const int xq = lane * 4;                       // 4 output cols per thread
  const int rw = t >> 6;                         // wave owns every 4th row
#pragma unroll
  for (int rr = rw; rr < DWR; rr += 4) {
    const float4 a0 = *(const float4*)&ls[(rr + 0) * 256 + xq];
    const float4 a1 = *(const float4*)&ls[(rr + 1) * 256 + xq];
    const float4 a2 = *(const float4*)&ls[(rr + 2) * 256 + xq];
    float vm0 = __shfl_up(a0.w, 1);
    float vm1 = __shfl_up(a1.w, 1);
    float vm2 = __shfl_up(a2.w, 1);
    float vp0 = __shfl_down(a0.x, 1);
    float vp1 = __shfl_down(a1.x, 1);
    float vp2 = __shfl_down(a2.x, 1);
    if (lane == 0)  { vm0 = 0.f; vm1 = 0.f; vm2 = 0.f; }
    if (lane == 63) { vp0 = 0.f; vp1 = 0.f; vp2 = 0.f; }
    const float r0e[6] = {vm0, a0.x, a0.y, a0.z, a0.w, vp0};
    const float r1e[6] = {vm1, a1.x, a1.y, a1.z, a1.w, vp1};
    const float r2e[6] = {vm2, a2.x, a2.y, a2.z, a2.w, vp2};
    float4 o;
    float* op = &o.x;
#pragma unroll
    for (int j = 0; j < 4; ++j) {
      float d = wv[0] * r0e[j] + wv[1] * r0e[j + 1] + wv[2] * r0e[j + 2];
      d = fmaf(wv[3], r1e[j], d);
      d = fmaf(wv[4], r1e[j + 1], d);
      d = fmaf(wv[5], r1e[j + 2], d);
      d = fmaf(wv[6], r2e[j], d);
      d = fmaf(wv[7], r2e[j + 1], d);
      d = fmaf(wv[8], r2e[j + 2], d);
      op[j] = d;
    }
    *(float4*)&ob[(r0 + rr) * W + xq] = o;
  }
}

// ============================ PATH A kernels =================================

// A1: 1x1 conv + depthwise 3x3 fused (fallback path only).
__global__ __launch_bounds__(256) void a1_conv_dw(
    const float* __restrict__ x, const float* __restrict__ w1,
    const float* __restrict__ w9, float* __restrict__ dwq,
    float* __restrict__ dwk, float* __restrict__ vout) {
  __shared__ float xs[C * 256];
  __shared__ float qs[8 * 256];
  __shared__ float wg[C * 8];
  __shared__ float wg9[8 * 9];
  const int t = threadIdx.x;
  const int bb = blockIdx.x / (NTX * NTY);
  const int tile = blockIdx.x % (NTX * NTY);
  const int ty = tile / NTX, tx = tile % NTX;
  const int hyy = t / HSX, hxx = t % HSX;
  const int hy = ty * TSY - 1 + hyy;
  const int hx = tx * TSX - 1 + hxx;
  const bool hin = (t < NHALO) && (hy >= 0) && (hy < H) && (hx >= 0) && (hx < W);
  const float* xb = x + (size_t)bb * C * HW + (hin ? (hy * W + hx) : 0);
#pragma unroll
  for (int ic = 0; ic < C; ++ic)
    xs[ic * 256 + t] = hin ? xb[(size_t)ic * HW] : 0.f;
  const int py = t / TSX, px = t % TSX;
  const int gy = ty * TSY + py, gx = tx * TSX + px;
  const bool pin = (t < NPIX2) && (gy < H);
  const int hpos = py * HSX + px;
  for (int grp = 0; grp < 18; ++grp) {
    const int ch0 = grp * 8;
    {
      const int j = t + ((t < 128) ? 256 : 0);
      if (t < 128) {
        const int ic = t >> 3, g = t & 7;
        wg[t] = w1[(ch0 + g) * C + ic];
        const int ic2 = j >> 3, g2 = j & 7;
        wg[j] = w1[(ch0 + g2) * C + ic2];
      } else if (t < 256) {
        const int r = t - 128;
        const int ic = (r + 128) >> 3, g = (r + 128) & 7;
        wg[r + 128] = w1[(ch0 + g) * C + ic];
      }
      if (t < 72) wg9[t] = w9[ch0 * 9 + t];
    }
    __syncthreads();
    float a[8];
#pragma unroll
    for (int g = 0; g < 8; ++g) a[g] = 0.f;
#pragma unroll 4
    for (int ic = 0; ic < C; ++ic) {
      const float xsv = xs[ic * 256 + t];
      const float4 w0 = *(const float4*)&wg[ic * 8];
      const float4 w4 = *(const float4*)&wg[ic * 8 + 4];
      a[0] = fmaf(w0.x, xsv, a[0]);
      a[1] = fmaf(w0.y, xsv, a[1]);
      a[2] = fmaf(w0.z, xsv, a[2]);
      a[3] = fmaf(w0.w, xsv, a[3]);
      a[4] = fmaf(w4.x, xsv, a[4]);
      a[5] = fmaf(w4.y, xsv, a[5]);
      a[6] = fmaf(w4.z, xsv, a[6]);
      a[7] = fmaf(w4.w, xsv, a[7]);
    }
#pragma unroll
    for (int g = 0; g < 8; ++g) qs[g * 256 + t] = a[g];
    __syncthreads();
    if (t < NPIX2) {
#pragma unroll
      for (int g = 0; g < 8; ++g) {
        const int ch = ch0 + g;
        const float* w9p = wg9 + g * 9;
        const float* q = qs + g * 256 + hpos;
        float d = w9p[0] * q[0] + w9p[1] * q[1] + w9p[2] * q[2];
        d = fmaf(w9p[3], q[HSX], d);
        d = fmaf(w9p[4], q[HSX + 1], d);
        d = fmaf(w9p[5], q[HSX + 2], d);
        d = fmaf(w9p[6], q[2 * HSX], d);
        d = fmaf(w9p[7], q[2 * HSX + 1], d);
        d = fmaf(w9p[8], q[2 * HSX + 2], d);
        if (pin) {
          float* dst;
          int cc;
          if (ch < C)          { dst = dwq; cc = ch; }
          else if (ch < 2 * C) { dst = dwk; cc = ch - C; }
          else                 { dst = vout; cc = ch - 2 * C; }
          dst[((size_t)bb * C + cc) * HW + gy * W + gx] = d;
        }
      }
    }
    __syncthreads();
  }
}

// A2: per-chunk Gram partials + norm partials, register double-buffered (T14).
__global__ __launch_bounds__(256) void a2_gram(
    const float* __restrict__ dwq, const float* __restrict__ dwk,
    float* __restrict__ Sp, float* __restrict__ nqp, float* __restrict__ nkp) {
  __shared__ float qs[C * LP];
  __shared__ float ks[C * LP];
  const int tid = threadIdx.x;
  const int bb = blockIdx.x / NCHUNK;
  const int chunk = blockIdx.x % NCHUNK;
  const int base = chunk * CHUNK;
  const float* qb = dwq + (size_t)bb * C * HW + base;
  const float* kb = dwk + (size_t)bb * C * HW + base;
  const int c0 = (tid >> 4) * 3;
  const int d0 = (tid & 15) * 3;
  float acc[3][3] = {{0.f}};
  float nacc = 0.f;
  float4 rq[3], rk[3];
#pragma unroll
  for (int j = 0; j < 3; ++j) {
    const int f = tid + j * 256;
    const int cc = f >> 4, p4 = (f & 15) * 4;
    rq[j] = *(const float4*)&qb[(size_t)cc * HW + p4];
    rk[j] = *(const float4*)&kb[(size_t)cc * HW + p4];
  }
  for (int sub = 0; sub < CHUNK / 64; ++sub) {
    __syncthreads();
#pragma unroll
    for (int j = 0; j < 3; ++j) {
      const int f = tid + j * 256;
      const int cc = f >> 4, p4 = (f & 15) * 4;
      *(float4*)&qs[cc * LP + p4] = rq[j];
      *(float4*)&ks[cc * LP + p4] = rk[j];
    }
    if (sub < CHUNK / 64 - 1) {
#pragma unroll
      for (int j = 0; j < 3; ++j) {
        const int f = tid + j * 256;
        const int cc = f >> 4, p4 = (f & 15) * 4;
        rq[j] = *(const float4*)&qb[(size_t)cc * HW + (sub + 1) * 64 + p4];
        rk[j] = *(const float4*)&kb[(size_t)cc * HW + (sub + 1) * 64 + p4];
      }
    }
    __syncthreads();
    if (tid < C) {
#pragma unroll
      for (int pq = 0; pq < 64; pq += 4) {
        const float4 v = *(const float4*)&qs[tid * LP + pq];
        nacc = fmaf(v.x, v.x, nacc);
        nacc = fmaf(v.y, v.y, nacc);
        nacc = fmaf(v.z, v.z, nacc);
        nacc = fmaf(v.w, v.w, nacc);
      }
    } else if (tid >= 64 && tid < 64 + C) {
      const int cq = tid - 64;
#pragma unroll
      for (int pq = 0; pq < 64; pq += 4) {
        const float4 v = *(const float4*)&ks[cq * LP + pq];
        nacc = fmaf(v.x, v.x, nacc);
        nacc = fmaf(v.y, v.y, nacc);
        nacc = fmaf(v.z, v.z, nacc);
        nacc = fmaf(v.w, v.w, nacc);
      }
    }
#pragma unroll 4
    for (int pq = 0; pq < 64; pq += 4) {
      const float4 q0 = *(const float4*)&qs[(c0 + 0) * LP + pq];
      const float4 q1 = *(const float4*)&qs[(c0 + 1) * LP + pq];
      const float4 q2 = *(const float4*)&qs[(c0 + 2) * LP + pq];
      const float4 k0 = *(const float4*)&ks[(d0 + 0) * LP + pq];
      const float4 k1 = *(const float4*)&ks[(d0 + 1) * LP + pq];
      const float4 k2 = *(const float4*)&ks[(d0 + 2) * LP + pq];
      const float qa[3][4] = {{q0.x, q0.y, q0.z, q0.w},
                              {q1.x, q1.y, q1.z, q1.w},
                              {q2.x, q2.y, q2.z, q2.w}};
      const float ka[3][4] = {{k0.x, k0.y, k0.z, k0.w},
                              {k1.x, k1.y, k1.z, k1.w},
                              {k2.x, k2.y, k2.z, k2.w}};
#pragma unroll
      for (int p = 0; p < 4; ++p)
#pragma unroll
        for (int i = 0; i < 3; ++i)
#pragma unroll
          for (int j = 0; j < 3; ++j)
            acc[i][j] = fmaf(qa[i][p], ka[j][p], acc[i][j]);
    }
  }
  float* Sb = Sp + ((size_t)bb * NCHUNK + chunk) * C * C;
#pragma unroll
  for (int i = 0; i < 3; ++i)
#pragma unroll
    for (int j = 0; j < 3; ++j)
      Sb[(c0 + i) * C + (d0 + j)] = acc[i][j];
  if (tid < C)                        nqp[((size_t)bb * NCHUNK + chunk) * C + tid] = nacc;
  else if (tid >= 64 && tid < 64 + C) nkp[((size_t)bb * NCHUNK + chunk) * C + (tid - 64)] = nacc;
}

// A3a: flat parallel reduction of the chunk partials (one thread/output).
#define RED_N (B * C * C + 2 * B * C)   // 9600
__global__ __launch_bounds__(256) void a3a_reduce(
    const float* __restrict__ Sp, const float* __restrict__ nqp,
    const float* __restrict__ nkp, float* __restrict__ S,
    float* __restrict__ nq, float* __restrict__ nk) {
  const int gid = blockIdx.x * 256 + threadIdx.x;
  if (gid < B * C * C) {
    const int bb = gid / (C * C), j = gid - bb * (C * C);
    const float* src = Sp + (size_t)bb * NCHUNK * C * C + j;
    float s = 0.f;
#pragma unroll 8
    for (int i = 0; i < NCHUNK; ++i) s += src[(size_t)i * C * C];
    S[gid] = s;
  } else if (gid < B * C * C + B * C) {
    const int r = gid - B * C * C;
    const int bb = r / C, j = r - bb * C;
    const float* src = nqp + (size_t)bb * NCHUNK * C + j;
    float s = 0.f;
#pragma unroll 8
    for (int i = 0; i < NCHUNK; ++i) s += src[(size_t)i * C];
    nq[r] = s;
  } else if (gid < RED_N) {
    const int r = gid - B * C * C - B * C;
    const int bb = r / C, j = r - bb * C;
    const float* src = nkp + (size_t)bb * NCHUNK * C + j;
    float s = 0.f;
#pragma unroll 8
    for (int i = 0; i < NCHUNK; ++i) s += src[(size_t)i * C];
    nk[r] = s;
  }
}

// A3b: normalize S, softmax rows, fold proj; writes transposed MT[d][e].
__global__ __launch_bounds__(64) void a3b_attn(
    const float* __restrict__ S, const float* __restrict__ nq,
    const float* __restrict__ nk, const float* __restrict__ proj_w,
    const float* __restrict__ temperature, float* __restrict__ MT) {
  __shared__ float A[C * C];
  __shared__ float knl[C];
  const int bb = blockIdx.x;
  const int t = threadIdx.x;
  const float T = temperature[0];
  if (t < C) knl[t] = fmaxf(sqrtf(nk[bb * C + t]), EPSN);
  __syncthreads();
  if (t < C) {
    const float qn = fmaxf(sqrtf(nq[bb * C + t]), EPSN);
    float row[C];
    float m = -1e30f;
    for (int d = 0; d < C; ++d) {
      const float v = S[(size_t)bb * C * C + t * C + d] / (qn * knl[d]) * T;
      row[d] = v;
      m = fmaxf(m, v);
    }
    float sum = 0.f;
    for (int d = 0; d < C; ++d) { const float e = expf(row[d] - m); row[d] = e; sum += e; }
    const float inv = 1.f / sum;
    for (int d = 0; d < C; ++d) A[t * C + d] = row[d] * inv;
  }
  __syncthreads();
  for (int idx = t; idx < C * C; idx += 64) {
    const int e = idx / C, d = idx % C;
    float acc = 0.f;
    for (int cc = 0; cc < C; ++cc) acc = fmaf(proj_w[e * C + cc], A[cc * C + d], acc);
    MT[(size_t)bb * C * C + d * C + e] = acc;
  }
}

// A4: out[e,p] = sum_d MT[d,e]*v[d,p], in place on d_out. 128-px tile
// (24 KB -> 6 blocks/CU), 2 px/thread, MT rows via wave-uniform s_load.
__global__ __launch_bounds__(256) void a4_apply(
    float* __restrict__ out, const float* __restrict__ MT) {
  __shared__ float vs[C * 128];  // 24 KB
  const int t = threadIdx.x;
  const int bb = blockIdx.x >> 9;                // 512 tiles per batch
  const int p0 = (blockIdx.x & 511) << 7;        // 128 px per tile
  float* ob = out + (size_t)bb * C * HW + p0;
#pragma unroll
  for (int j = 0; j < 6; ++j) {                  // 1536 float4 = 48x128
    const int f = t + j * 256;
    const int d = f >> 5, p4 = (f & 31) * 4;
    *(float4*)&vs[d * 128 + p4] = *(const float4*)&ob[(size_t)d * HW + p4];
  }
  __syncthreads();
  const int pl = (t & 63) * 2;
  const int e0 = __builtin_amdgcn_readfirstlane((t >> 6) * 12);
  const float* mb = MT + (size_t)bb * C * C + e0;  // uniform -> s_load
  float acc[12][2];
#pragma unroll
  for (int o = 0; o < 12; ++o)
#pragma unroll
    for (int p = 0; p < 2; ++p) acc[o][p] = 0.f;
#pragma unroll 4
  for (int d = 0; d < C; ++d) {
    const float2 xv = *(const float2*)&vs[d * 128 + pl];
    const float xa[2] = {xv.x, xv.y};
#pragma unroll
    for (int jj = 0; jj < 3; ++jj) {
      const float4 wv = *(const float4*)&mb[d * C + jj * 4];
      const float wa[4] = {wv.x, wv.y, wv.z, wv.w};
#pragma unroll
      for (int o = 0; o < 4; ++o)
#pragma unroll
        for (int p = 0; p < 2; ++p)
          acc[jj * 4 + o][p] = fmaf(wa[o], xa[p], acc[jj * 4 + o][p]);
    }
  }
#pragma unroll
  for (int o = 0; o < 12; ++o) {
    float2 v;
    v.x = acc[o][0]; v.y = acc[o][1];
    *(float2*)&ob[(size_t)(e0 + o) * HW + pl] = v;
  }
}

// ==================== PATH B (fallback) kernels ==============================

__global__ __launch_bounds__(256) void k0_zero(float* __restrict__ ws) {
  const int i = blockIdx.x * 256 + threadIdx.x;
  if (i < B_ZERO_N) ws[i] = 0.f;
}

#define TS 14
#define HS 16
#define NT 19
#define NPIX 196

__global__ __launch_bounds__(256) void k1_fused(
    const float* __restrict__ x, const float* __restrict__ w1,
    const float* __restrict__ w9, float* __restrict__ vout,
    float* __restrict__ S, float* __restrict__ nq, float* __restrict__ nk) {
  __shared__ float qs[4 * 256];
  __shared__ float qt[NPIX * C];
  __shared__ float kt[NPIX * C];
  const int t = threadIdx.x;
  const int bb = blockIdx.x / (NT * NT);
  const int tile = blockIdx.x % (NT * NT);
  const int ty = tile / NT, tx = tile % NT;
  const int hy = ty * TS - 1 + (t >> 4);
  const int hx = tx * TS - 1 + (t & 15);
  const bool hin = (hy >= 0 && hy < H && hx >= 0 && hx < W);
  const float* xb = x + (size_t)bb * C * HW;
  float xv[C];
#pragma unroll
  for (int ic = 0; ic < C; ++ic)
    xv[ic] = hin ? xb[(size_t)ic * HW + hy * W + hx] : 0.f;
  const int py = t / TS, px = t % TS;
  const int gy = ty * TS + py, gx = tx * TS + px;
  const bool pin = (t < NPIX) && (gy < H) && (gx < W);
  for (int grp = 0; grp < 36; ++grp) {
    const int ch0 = grp * 4;
    const float* wp = w1 + ch0 * C;
    float a0 = 0.f, a1 = 0.f, a2 = 0.f, a3 = 0.f;
#pragma unroll
    for (int ic = 0; ic < C; ++ic) {
      const float xs = xv[ic];
      a0 = fmaf(wp[ic], xs, a0);
      a1 = fmaf(wp[C + ic], xs, a1);
      a2 = fmaf(wp[2 * C + ic], xs, a2);
      a3 = fmaf(wp[3 * C + ic], xs, a3);
    }
    qs[0 * 256 + t] = a0;
    qs[1 * 256 + t] = a1;
    qs[2 * 256 + t] = a2;
    qs[3 * 256 + t] = a3;
    __syncthreads();
    if (t < NPIX) {
#pragma unroll
      for (int g = 0; g < 4; ++g) {
        const int ch = ch0 + g;
        const float* w9p = w9 + ch * 9;
        const float* q = qs + g * 256 + py * HS + px;
        float d = w9p[0] * q[0] + w9p[1] * q[1] + w9p[2] * q[2];
        d = fmaf(w9p[3], q[HS], d);
        d = fmaf(w9p[4], q[HS + 1], d);
        d = fmaf(w9p[5], q[HS + 2], d);
        d = fmaf(w9p[6], q[2 * HS], d);
        d = fmaf(w9p[7], q[2 * HS + 1], d);
        d = fmaf(w9p[8], q[2 * HS + 2], d);
        if (ch < C)          qt[t * C + ch] = pin ? d : 0.f;
        else if (ch < 2 * C) kt[t * C + (ch - C)] = pin ? d : 0.f;
        else if (pin)        vout[((size_t)bb * C + (ch - 2 * C)) * HW + gy * W + gx] = d;
      }
    }
    __syncthreads();
  }
  if (t < C) {
    float s = 0.f;
    for (int p = 0; p < NPIX; ++p) { const float v = qt[p * C + t]; s = fmaf(v, v, s); }
    atomicAdd(&nq[bb * C + t], s);
  } else if (t >= 64 && t < 64 + C) {
    const int c = t - 64;
    float s = 0.f;
    for (int p = 0; p < NPIX; ++p) { const float v = kt[p * C + c]; s = fmaf(v, v, s); }
    atomicAdd(&nk[bb * C + c], s);
  }
  {
    const int part = t >> 6;
    const int idx = t & 63;
    const int c0 = (idx >> 3) * 6;
    const int d0 = (idx & 7) * 6;
    float acc[6][6] = {{0.f}};
    const int p0 = part * 49;
    for (int p = p0; p < p0 + 49; ++p) {
      float qv[6], kv[6];
#pragma unroll
      for (int j = 0; j < 6; ++j) { qv[j] = qt[p * C + c0 + j]; kv[j] = kt[p * C + d0 + j]; }
#pragma unroll
      for (int i = 0; i < 6; ++i)
#pragma unroll
        for (int j = 0; j < 6; ++j) acc[i][j] = fmaf(qv[i], kv[j], acc[i][j]);
    }
    float* Sb = S + (size_t)bb * C * C;
#pragma unroll
    for (int i = 0; i < 6; ++i)
#pragma unroll
      for (int j = 0; j < 6; ++j) atomicAdd(&Sb[(c0 + i) * C + (d0 + j)], acc[i][j]);
  }
}

// =============================================================================

extern "C" void kernel_launch(void* const* d_in, const int* in_sizes, int n_in,
                              void* d_out, int out_size, void* d_ws, size_t ws_size,
                              hipStream_t stream) {
  const float* x      = (const float*)d_in[0];
  const float* qkv_w  = (const float*)d_in[1];
  const float* dw_w   = (const float*)d_in[2];
  const float* proj_w = (const float*)d_in[3];
  const float* temp   = (const float*)d_in[4];
  float* out = (float*)d_out;
  float* ws  = (float*)d_ws;

  if (ws_size >= S_FLOATS * sizeof(float)) {
    float* qkv = ws + S_QKV_OFF;
    float* dwq = ws + S_DWQ_OFF;
    float* dwk = ws + S_DWK_OFF;
    float* Sp  = ws + S_SP_OFF;
    float* nqp = ws + S_NQP_OFF;
    float* nkp = ws + S_NKP_OFF;
    float* S   = ws + S_S_OFF;
    float* nq  = ws + S_NQ_OFF;
    float* nk  = ws + S_NK_OFF;
    float* MT  = ws + S_M_OFF;
    float* wT  = ws + S_WT_OFF;
    s_wt<<<(C3 * C + 255) / 256, 256, 0, stream>>>(qkv_w, wT);
    s_conv1x1<<<B * 512, 256, 0, stream>>>(x, wT, qkv);
    s_dw<<<B * C3 * (H / DWR), 256, 0, stream>>>(qkv, dw_w, dwq, dwk, out);
    a2_gram<<<B * NCHUNK, 256, 0, stream>>>(dwq, dwk, Sp, nqp, nkp);
    a3a_reduce<<<(RED_N + 255) / 256, 256, 0, stream>>>(Sp, nqp, nkp, S, nq, nk);
    a3b_attn<<<B, 64, 0, stream>>>(S, nq, nk, proj_w, temp, MT);
    a4_apply<<<B * 512, 256, 0, stream>>>(out, MT);
  } else if (ws_size >= A_FLOATS * sizeof(float)) {
    float* dwq = ws + A_DWQ_OFF;
    float* dwk = ws + A_DWK_OFF;
    float* Sp  = ws + A_SP_OFF;
    float* nqp = ws + A_NQP_OFF;
    float* nkp = ws + A_NKP_OFF;
    float* S   = ws + A_S_OFF;
    float* nq  = ws + A_NQ_OFF;
    float* nk  = ws + A_NK_OFF;
    float* MT  = ws + A_M_OFF;
    a1_conv_dw<<<B * NTX * NTY, 256, 0, stream>>>(x, qkv_w, dw_w, dwq, dwk, out);
    a2_gram<<<B * NCHUNK, 256, 0, stream>>>(dwq, dwk, Sp, nqp, nkp);
    a3a_reduce<<<(RED_N + 255) / 256, 256, 0, stream>>>(Sp, nqp, nkp, S, nq, nk);
    a3b_attn<<<B, 64, 0, stream>>>(S, nq, nk, proj_w, temp, MT);
    a4_apply<<<B * 512, 256, 0, stream>>>(out, MT);
  } else {
    float* S  = ws + B_S_OFF;
    float* nq = ws + B_NQ_OFF;
    float* nk = ws + B_NK_OFF;
    float* MT = ws + B_M_OFF;
    k0_zero<<<(B_ZERO_N + 255) / 256, 256, 0, stream>>>(ws);
    k1_fused<<<B * NT * NT, 256, 0, stream>>>(x, qkv_w, dw_w, out, S, nq, nk);
    a3b_attn<<<B, 64, 0, stream>>>(S, nq, nk, proj_w, temp, MT);
    a4_apply<<<B * 512, 256, 0, stream>>>(out, MT);
  }
}